// Round 5
// baseline (262.981 us; speedup 1.0000x reference)
//
#include <hip/hip_runtime.h>
#include <math.h>

// B=128, N=64, D=2, H=64, M=64, L=2. f32 in / f32 out.
// R22 = R21 (verified 225.7/229.2) + k_mean fused into k_L1 via relaxed
// device-scope atomics (4 -> 3 launches).
// Session model (R18-R21 counters): kernels sum ~150us vs ~229 total ->
// ~14-15us per launch slot (R19: +1 launch = +14.6 with k_L0 flat).
// Container noise: identical source measured k_L0 74.5 vs 69.3 (+-7%) — only
// structural deltas are benchable.
// R15/R16 lesson: NO __threadfence / acquire-release at agent scope (emits
// buffer_wbl2/inv -> L2 wb/inv on non-coherent XCD L2s; destroyed he0g
// residency, FETCH 10->46MB, k_L1 345us). This fusion uses ONLY relaxed
// device-scope atomics on 64KB (dxv/dxa/cnt) + s_waitcnt vmcnt(0) (pure wait,
// no cache maintenance). Last-arriver-per-b block writes the final output.
// Merged weights: SA=ew2@w1he0, SB=w2_0@u1_0(+biasB), SC=w2_0@w1he1, SD=w2_1@u1_1(+biasD);
// p0' carries b1_0+eb2@w1he0; p1' carries b1n+b2_0@w1he1 (biasC).
// MFMA fragment addressing identical to R9-R14 (verified).

typedef unsigned short u16;
typedef unsigned int u32;
typedef _Float16 half8 __attribute__((ext_vector_type(8)));   // 4 VGPR frag
typedef __attribute__((ext_vector_type(4))) float floatx4;

#define TS 72            // LDS tile row stride (f16): 144 B
#define HROW 72          // he0g row stride (u16) — mirrors LDS tile
#define HBLK (64 * HROW) // 4608 u16 per block

// gelu via A&S 7.1.27 rational erf (|eps|<=5e-4), no exp (R14-verified)
__device__ __forceinline__ float gelu_f(float x) {
    float s = fabsf(x) * 0.70710678118654752f;
    float q = fmaf(fmaf(fmaf(fmaf(0.078108f, s, 0.000972f), s, 0.230389f), s, 0.278393f), s, 1.0f);
    float q2 = q * q;
    float r = __builtin_amdgcn_rcpf(q2 * q2);
    float t = 0.5f * x * r;
    return x > 0.f ? x - t : t;
}

// k_pre: blocks [0,64): 4 merged 64x64 products -> WF f16 frag layout;
//        block 64: bias vectors + zero cnt/dxa; blocks [65,129): 4 f32 transposes;
//        blocks [129,2177): node MLP + p0' (biasA fold inline), 4 nodes/block.
__global__ __launch_bounds__(256) void k_pre(
    const float* __restrict__ ew2, const float* __restrict__ w1he0,
    const float* __restrict__ w2_0, const float* __restrict__ u1_0,
    const float* __restrict__ w1he1, const float* __restrict__ w2_1,
    const float* __restrict__ u1_1,
    const float* __restrict__ eb2, const float* __restrict__ b2_0,
    const float* __restrict__ c1_0, const float* __restrict__ b2_1,
    const float* __restrict__ c1_1,
    const float* __restrict__ b1_0v, const float* __restrict__ b1nv,
    const float* __restrict__ u2_0, const float* __restrict__ u2_1,
    const float* __restrict__ w1n, const float* __restrict__ hw1,
    _Float16* __restrict__ WF,
    float* __restrict__ biasB, float* __restrict__ biasC, float* __restrict__ biasD,
    float* __restrict__ u2_0T, float* __restrict__ u2_1T,
    float* __restrict__ w1nT, float* __restrict__ hw1T,
    const float* __restrict__ x, const float* __restrict__ spin,
    const float* __restrict__ nw1, const float* __restrict__ nb1,
    const float* __restrict__ nw2, const float* __restrict__ nb2,
    const float* __restrict__ w1_0,
    float* __restrict__ hv, float* __restrict__ p0,
    float* __restrict__ dxa, u32* __restrict__ cnt)
{
    int blk = blockIdx.x;
    if (blk < 64) {
        int s = blk >> 4;                               // product id
        int idx = (blk & 15) * 256 + threadIdx.x;       // 0..4095
        int k = idx >> 6, n = idx & 63;
        const float *A, *Bm;
        if (s == 0)      { A = ew2;  Bm = w1he0; }
        else if (s == 1) { A = w2_0; Bm = u1_0;  }
        else if (s == 2) { A = w2_0; Bm = w1he1; }
        else             { A = w2_1; Bm = u1_1;  }
        float acc = 0.f;
        for (int q = 0; q < 64; ++q) acc = fmaf(A[k * 64 + q], Bm[q * 64 + n], acc);
        int kc = k >> 5, qd = (k >> 3) & 3, jj = k & 7;
        WF[(((s * 2 + kc) * 64 + n) * 4 + qd) * 8 + jj] = (_Float16)acc;
    } else if (blk == 64) {
        int s = threadIdx.x >> 6, cc = threadIdx.x & 63;
        if (s == 0) {
            // zero the fused-mean accumulators (re-zeroed every graph iteration)
            cnt[cc] = 0u; cnt[64 + cc] = 0u;
            float4 z4 = make_float4(0.f, 0.f, 0.f, 0.f);
            ((float4*)dxa)[cc] = z4;                    // 256 floats
        } else {
            const float *bv, *Bm, *add; float* dst;
            if (s == 1)      { bv = b2_0; Bm = u1_0;  add = c1_0; dst = biasB; }
            else if (s == 2) { bv = b2_0; Bm = w1he1; add = b1nv; dst = biasC; }
            else             { bv = b2_1; Bm = u1_1;  add = c1_1; dst = biasD; }
            float acc = add[cc];
            for (int q = 0; q < 64; ++q) acc = fmaf(bv[q], Bm[q * 64 + cc], acc);
            dst[cc] = acc;
        }
    } else if (blk < 129) {
        int idx = (blk - 65) * 256 + threadIdx.x;       // 0..16383
        int s = idx >> 12, r = idx & 4095, m = r >> 6, tc = r & 63;
        const float* W = s == 0 ? u2_0 : s == 1 ? u2_1 : s == 2 ? w1n : hw1;
        float* WT      = s == 0 ? u2_0T : s == 1 ? u2_1T : s == 2 ? w1nT : hw1T;
        WT[tc * 64 + m] = W[m * 64 + tc];
    } else {
        __shared__ float a[4][64];
        __shared__ float shv[4][64];
        int w = threadIdx.x >> 6, h = threadIdx.x & 63;
        int node = (blk - 129) * 4 + w;
        float2 xv = ((const float2*)x)[node];
        float sp = spin[node];
        float z = fmaf(xv.x, nw1[h], fmaf(xv.y, nw1[64 + h], fmaf(sp, nw1[128 + h], nb1[h])));
        a[w][h] = gelu_f(z);                         // wave-synchronous slice
        float acc = nb2[h];
        for (int k = 0; k < 64; ++k) acc = fmaf(a[w][k], nw2[k * 64 + h], acc);
        hv[node * 64 + h] = acc;
        shv[w][h] = acc;
        // p0' = b1_0 + eb2@w1he0 (biasA fold, inline) + hv@w1_0
        float pa = b1_0v[h];
        for (int q = 0; q < 64; ++q) pa = fmaf(eb2[q], w1he0[q * 64 + h], pa);
        for (int k = 0; k < 64; ++k) pa = fmaf(shv[w][k], w1_0[k * 64 + h], pa);
        p0[node * 64 + h] = pa;
    }
}

// accumulate one 64x64 stage into pre-initialized acc; A from LDS (R9-verified)
__device__ __forceinline__ void mfma_acc(
    const _Float16* __restrict__ tA, const _Float16* __restrict__ WF,
    int stage, int c, int quad, int nn, floatx4 acc[4])
{
    int sA = ((nn >> 2) & 3) << 3;
    #pragma unroll
    for (int kc = 0; kc < 2; ++kc) {
        half8 bf = *(const half8*)(WF + (((stage * 2 + kc) * 64 + c) * 4 + quad) * 8);
        int k0 = (kc * 32 + quad * 8) ^ sA;
        #pragma unroll
        for (int mt = 0; mt < 4; ++mt) {
            half8 af = *(const half8*)(tA + (mt * 16 + nn) * TS + k0);
            acc[mt] = __builtin_amdgcn_mfma_f32_16x16x32_f16(af, bf, acc[mt], 0, 0, 0);
        }
    }
}

__device__ __forceinline__ void init_bias(floatx4 acc[4], float bc) {
    #pragma unroll
    for (int mt = 0; mt < 4; ++mt) acc[mt] = (floatx4){bc, bc, bc, bc};
}
__device__ __forceinline__ void init_p(floatx4 acc[4], const float* __restrict__ p,
                                       int rowbase, int c, int quad) {
    #pragma unroll
    for (int mt = 0; mt < 4; ++mt)
        #pragma unroll
        for (int r = 0; r < 4; ++r)
            acc[mt][r] = p[(rowbase + mt * 16 + quad * 4 + r) * 64 + c];
}

__global__ __launch_bounds__(256, 8) void k_L0(
    const float* __restrict__ x,
    const float* __restrict__ ew1, const float* __restrict__ eb1,
    const float* __restrict__ p0,        // p0' (biasA folded)
    const float* __restrict__ biasB,
    const float* __restrict__ u2_0T, const float* __restrict__ c2_0,
    const _Float16* __restrict__ WF,
    const float* __restrict__ hv0, float* __restrict__ hv1,
    const float* __restrict__ w1nT, const float* __restrict__ biasC,
    float* __restrict__ p1,
    u16* __restrict__ he0g)
{
    __shared__ __align__(16) _Float16 tA[64 * TS];
    __shared__ float sS[64];
    __shared__ float shv[64];
    __shared__ float sred[256];
    int t = threadIdx.x, L = t & 63;
    int w = __builtin_amdgcn_readfirstlane(t >> 6);
    int nn = L & 15, quad = L >> 4;
    int c = w * 16 + nn;
    int cw = c ^ (quad << 3);
    int b = blockIdx.x >> 6, j = blockIdx.x & 63;

    // geometry in registers: lane = i = L
    float2 xi = ((const float2*)x)[b * 64 + L];
    float2 xj = ((const float2*)x)[b * 64 + j];
    float d0 = xj.x - xi.x, d1 = xj.y - xi.y;     // dr = x_j - x_i
    float r2 = fmaf(d0, d0, d1 * d1);
    float rr = sqrtf(r2 + 1e-12f);
    int swL = ((L >> 2) & 3) << 3;

    // g1 row L, m in [w*16, w*16+16): SGPR weights, packed b128 writes
    #pragma unroll
    for (int mb = 0; mb < 2; ++mb) {
        int m0 = w * 16 + mb * 8;
        half8 h8;
        #pragma unroll
        for (int kk = 0; kk < 8; ++kk) {
            int m = m0 + kk;
            float z = fmaf(d0, ew1[m], fmaf(d1, ew1[64 + m],
                      fmaf(rr, ew1[128 + m], fmaf(r2, ew1[192 + m], eb1[m]))));
            h8[kk] = (_Float16)gelu_f(z);
        }
        *(half8*)(tA + L * TS + (m0 ^ swL)) = h8;
    }
    __syncthreads();

    floatx4 acc[4];
    // M1: z0 = p0' + g1 @ SA -> Y = gelu; store Y to LDS + he0g (row stride 72)
    init_p(acc, p0, b * 64, c, quad);
    mfma_acc(tA, WF, 0, c, quad, nn, acc);
    __syncthreads();
    {
        u16* dst = he0g + (size_t)blockIdx.x * HBLK;
        #pragma unroll
        for (int mt = 0; mt < 4; ++mt)
            #pragma unroll
            for (int r = 0; r < 4; ++r) {
                int i = mt * 16 + quad * 4 + r;
                _Float16 y = (_Float16)gelu_f(acc[mt][r]);
                tA[i * TS + cw] = y;
                dst[i * HROW + cw] = __builtin_bit_cast(u16, y);
            }
    }
    __syncthreads();
    // M2: a = gelu(Y @ SB + biasB); masked i-sum -> sS
    init_bias(acc, biasB[c]);
    mfma_acc(tA, WF, 1, c, quad, nn, acc);
    {
        float s = 0.f;
        #pragma unroll
        for (int mt = 0; mt < 4; ++mt)
            #pragma unroll
            for (int r = 0; r < 4; ++r) {
                int i = mt * 16 + quad * 4 + r;
                float g = gelu_f(acc[mt][r]);
                s += (i == j) ? 0.f : g;
            }
        s += __shfl_xor(s, 16);
        s += __shfl_xor(s, 32);
        if (quad == 0) sS[c] = s;
    }
    __syncthreads();
    // tail phase A: hv1 (parallel over 256)
    {
        const float4* sv4 = (const float4*)(sS + w * 16);
        const float4* uv4 = (const float4*)(u2_0T + L * 64 + w * 16);
        float g = 0.f;
        #pragma unroll
        for (int m4 = 0; m4 < 4; ++m4) {
            float4 sv = sv4[m4], uv = uv4[m4];
            g = fmaf(sv.x, uv.x, fmaf(sv.y, uv.y, fmaf(sv.z, uv.z, fmaf(sv.w, uv.w, g))));
        }
        sred[w * 64 + L] = g;
    }
    __syncthreads();
    if (t < 64) {
        float g = sred[t] + sred[64 + t] + sred[128 + t] + sred[192 + t];
        int o = blockIdx.x * 64 + t;
        float hvv = hv0[o] + g * (1.0f / 63.0f) + c2_0[t];
        hv1[o] = hvv;
        shv[t] = hvv;
    }
    __syncthreads();
    // tail phase B: p1' (parallel over 256)
    {
        const float4* hv4 = (const float4*)(shv + w * 16);
        const float4* wv4 = (const float4*)(w1nT + L * 64 + w * 16);
        float pa = 0.f;
        #pragma unroll
        for (int m4 = 0; m4 < 4; ++m4) {
            float4 sv = hv4[m4], uv = wv4[m4];
            pa = fmaf(sv.x, uv.x, fmaf(sv.y, uv.y, fmaf(sv.z, uv.z, fmaf(sv.w, uv.w, pa))));
        }
        sred[w * 64 + L] = pa;
    }
    __syncthreads();
    if (t < 64)
        p1[blockIdx.x * 64 + t] = biasC[t] + sred[t] + sred[64 + t] + sred[128 + t] + sred[192 + t];
}

__global__ __launch_bounds__(256, 8) void k_L1(
    const u16* __restrict__ he0g,
    const float* __restrict__ p1,        // p1' (biasC folded)
    const float* __restrict__ biasD,
    const float* __restrict__ u2_1T, const float* __restrict__ c2_1,
    const _Float16* __restrict__ WF,
    const float* __restrict__ hv1,
    const float* __restrict__ hw1T, const float* __restrict__ hb1,
    const float* __restrict__ hw2, const float* __restrict__ hb2,
    const float* __restrict__ scale,
    float* __restrict__ dxv, float* __restrict__ dxa, u32* __restrict__ cnt,
    float* __restrict__ out)
{
    __shared__ __align__(16) _Float16 tA[64 * TS];
    __shared__ float sS[64];
    __shared__ float shv[64];
    __shared__ float sred[256];
    __shared__ int slast;
    int t = threadIdx.x, L = t & 63;
    int w = __builtin_amdgcn_readfirstlane(t >> 6);
    int nn = L & 15, quad = L >> 4;
    int c = w * 16 + nn;
    int cw = c ^ (quad << 3);
    int b = blockIdx.x >> 6, j = blockIdx.x & 63;

    {   // Y load: he0g layout mirrors LDS tile exactly -> linear float4 copy
        const float4* src = (const float4*)(he0g + (size_t)blockIdx.x * HBLK);
        float4* dstl = (float4*)tA;
        for (int q = t; q < (HBLK * 2 / 16); q += 256)   // 576 chunks
            dstl[q] = src[q];
    }
    __syncthreads();

    floatx4 acc[4];
    // M3: z1 = p1' + Y @ SC -> Y2 = gelu
    init_p(acc, p1, b * 64, c, quad);
    mfma_acc(tA, WF, 2, c, quad, nn, acc);
    __syncthreads();
    #pragma unroll
    for (int mt = 0; mt < 4; ++mt)
        #pragma unroll
        for (int r = 0; r < 4; ++r)
            tA[(mt * 16 + quad * 4 + r) * TS + cw] = (_Float16)gelu_f(acc[mt][r]);
    __syncthreads();
    // M4: a = gelu(Y2 @ SD + biasD); masked i-sum -> sS
    init_bias(acc, biasD[c]);
    mfma_acc(tA, WF, 3, c, quad, nn, acc);
    {
        float s = 0.f;
        #pragma unroll
        for (int mt = 0; mt < 4; ++mt)
            #pragma unroll
            for (int r = 0; r < 4; ++r) {
                int i = mt * 16 + quad * 4 + r;
                float g = gelu_f(acc[mt][r]);
                s += (i == j) ? 0.f : g;
            }
        s += __shfl_xor(s, 16);
        s += __shfl_xor(s, 32);
        if (quad == 0) sS[c] = s;
    }
    __syncthreads();
    // tail phase A: hv2
    {
        const float4* sv4 = (const float4*)(sS + w * 16);
        const float4* uv4 = (const float4*)(u2_1T + L * 64 + w * 16);
        float g = 0.f;
        #pragma unroll
        for (int m4 = 0; m4 < 4; ++m4) {
            float4 sv = sv4[m4], uv = uv4[m4];
            g = fmaf(sv.x, uv.x, fmaf(sv.y, uv.y, fmaf(sv.z, uv.z, fmaf(sv.w, uv.w, g))));
        }
        sred[w * 64 + L] = g;
    }
    __syncthreads();
    if (t < 64) {
        float g = sred[t] + sred[64 + t] + sred[128 + t] + sred[192 + t];
        float hv2 = hv1[blockIdx.x * 64 + t] + g * (1.0f / 63.0f) + c2_1[t];
        shv[t] = hv2;
    }
    __syncthreads();
    // tail phase B: head layer-1 (parallel) -> tanh
    {
        const float4* hv4 = (const float4*)(shv + w * 16);
        const float4* wv4 = (const float4*)(hw1T + L * 64 + w * 16);
        float a = 0.f;
        #pragma unroll
        for (int m4 = 0; m4 < 4; ++m4) {
            float4 sv = hv4[m4], uv = wv4[m4];
            a = fmaf(sv.x, uv.x, fmaf(sv.y, uv.y, fmaf(sv.z, uv.z, fmaf(sv.w, uv.w, a))));
        }
        sred[w * 64 + L] = a;
    }
    __syncthreads();
    if (t < 64) {
        float a = hb1[t] + sred[t] + sred[64 + t] + sred[128 + t] + sred[192 + t];
        float t1 = tanhf(a);
        float dd0 = t1 * hw2[t * 2], dd1 = t1 * hw2[t * 2 + 1];
        #pragma unroll
        for (int off = 1; off <= 32; off <<= 1) { dd0 += __shfl_xor(dd0, off); dd1 += __shfl_xor(dd1, off); }
        if (t == 0) {
            float sp = log1pf(__expf(scale[0]));
            float v0 = (dd0 + hb2[0]) * sp;
            float v1 = (dd1 + hb2[1]) * sp;
            // device-scope relaxed atomics only — no fences, no acquire/release
            // (those emit L2 wb/inv on gfx950 = the R15/R16 disaster).
            atomicExch(&dxv[blockIdx.x * 2 + 0], v0);
            atomicExch(&dxv[blockIdx.x * 2 + 1], v1);
            atomicAdd(&dxa[b * 2 + 0], v0);
            atomicAdd(&dxa[b * 2 + 1], v1);
            asm volatile("s_waitcnt vmcnt(0)" ::: "memory");  // order: values before counter
            u32 old = atomicAdd(&cnt[b], 1u);
            slast = (old == 63u) ? 1 : 0;
        }
    }
    __syncthreads();
    // last-arriver block for batch b computes mean + writes final output
    if (slast && t < 64) {
        float m0 = __hip_atomic_load(&dxa[b * 2 + 0], __ATOMIC_RELAXED, __HIP_MEMORY_SCOPE_AGENT) * 0.015625f;
        float m1 = __hip_atomic_load(&dxa[b * 2 + 1], __ATOMIC_RELAXED, __HIP_MEMORY_SCOPE_AGENT) * 0.015625f;
        float v0 = __hip_atomic_load(&dxv[(b * 64 + t) * 2 + 0], __ATOMIC_RELAXED, __HIP_MEMORY_SCOPE_AGENT);
        float v1 = __hip_atomic_load(&dxv[(b * 64 + t) * 2 + 1], __ATOMIC_RELAXED, __HIP_MEMORY_SCOPE_AGENT);
        ((float2*)out)[b * 64 + t] = make_float2(v0 - m0, v1 - m1);
    }
}

__global__ void k_beacon(float* out, float code) { out[0] = code; }

extern "C" void kernel_launch(void* const* d_in, const int* in_sizes, int n_in,
                              void* d_out, int out_size, void* d_ws, size_t ws_size,
                              hipStream_t stream)
{
    static const int exp_sizes[23] = {
        16384, 8192, 192, 64, 4096, 64,
        256, 64, 4096, 64,
        16384, 128, 8192, 128,
        8192, 128, 8192, 128,
        4096, 64, 128, 2, 1
    };
    // ws layout
    float* hv0 = (float*)d_ws;                  // 524288 f
    float* hv1 = hv0 + 524288;
    float* p0  = hv1 + 524288;
    float* p1  = p0  + 524288;
    float* dxv = p1  + 524288;                  // 16384 f (per-(b,j) head values)
    float* u2_0T = dxv + 16384;                 // 4096 f
    float* u2_1T = u2_0T + 4096;
    float* w1nT  = u2_1T + 4096;
    float* hw1T  = w1nT + 4096;
    float* biasB = hw1T + 4096;                 // 3 x 64 f
    float* biasC = biasB + 64;
    float* biasD = biasC + 64;
    float* dxa   = biasD + 64;                  // 256 f (per-b sums)
    u32*   cnt   = (u32*)(dxa + 256);           // 128 u32
    _Float16* WF = (_Float16*)(cnt + 128);      // 16384 f16 (4 stages)
    u16* he0g  = (u16*)(WF + 16384);            // 8192*4608 u16 (75.5 MB)
    const size_t need = (size_t)((char*)(he0g + (size_t)8192 * HBLK) - (char*)d_ws);

    int bad = -1;
    if (n_in != 23 || out_size != 16384) bad = 98;
    else if (ws_size < need) bad = 97;
    else for (int i = 0; i < 23; ++i)
        if (in_sizes[i] != exp_sizes[i]) { bad = i; break; }
    if (bad >= 0) {
        k_beacon<<<1, 1, 0, stream>>>((float*)d_out, 2e6f + bad * 1e4f);
        return;
    }

    const float* x      = (const float*)d_in[0];
    const float* spin   = (const float*)d_in[1];
    const float* nw1    = (const float*)d_in[2];
    const float* nb1    = (const float*)d_in[3];
    const float* nw2    = (const float*)d_in[4];
    const float* nb2    = (const float*)d_in[5];
    const float* ew1    = (const float*)d_in[6];
    const float* eb1    = (const float*)d_in[7];
    const float* ew2    = (const float*)d_in[8];
    const float* eb2    = (const float*)d_in[9];
    const float* v2e_w1 = (const float*)d_in[10];
    const float* v2e_b1 = (const float*)d_in[11];
    const float* v2e_w2 = (const float*)d_in[12];
    const float* v2e_b2 = (const float*)d_in[13];
    const float* e2v_w1 = (const float*)d_in[14];
    const float* e2v_b1 = (const float*)d_in[15];
    const float* e2v_w2 = (const float*)d_in[16];
    const float* e2v_b2 = (const float*)d_in[17];
    const float* hw1    = (const float*)d_in[18];
    const float* hb1    = (const float*)d_in[19];
    const float* hw2    = (const float*)d_in[20];
    const float* hb2    = (const float*)d_in[21];
    const float* scale  = (const float*)d_in[22];

    // layer slices: w1he_l = v2e_w1 + l*8192 + 4096 (edge part); w1n_l = v2e_w1 + l*8192
    k_pre<<<2177, 256, 0, stream>>>(
        ew2, v2e_w1 + 4096, v2e_w2, e2v_w1,
        v2e_w1 + 12288, v2e_w2 + 4096, e2v_w1 + 4096,
        eb2, v2e_b2, e2v_b1, v2e_b2 + 64, e2v_b1 + 64,
        v2e_b1, v2e_b1 + 64,
        e2v_w2, e2v_w2 + 4096, v2e_w1 + 8192, hw1,
        WF, biasB, biasC, biasD,
        u2_0T, u2_1T, w1nT, hw1T,
        x, spin, nw1, nb1, nw2, nb2, v2e_w1, hv0, p0,
        dxa, cnt);
    k_L0<<<8192, 256, 0, stream>>>(x, ew1, eb1,
        p0, biasB, u2_0T, e2v_b2,
        WF, hv0, hv1,
        w1nT, biasC, p1,
        he0g);
    k_L1<<<8192, 256, 0, stream>>>(he0g,
        p1, biasD, u2_1T, e2v_b2 + 64,
        WF, hv1, hw1T, hb1, hw2, hb2, scale,
        dxv, dxa, cnt, (float*)d_out);
}

// Round 6
// 234.450 us; speedup vs baseline: 1.1217x; 1.1217x over previous
//
#include <hip/hip_runtime.h>
#include <math.h>

// B=128, N=64, D=2, H=64, M=64, L=2. f32 in / f32 out.
// R23 = R21 (3x-verified 225.7/226.9/229.2) + ONE single-variable rider:
// __launch_bounds__(256,8)->(256,6) on k_L0/k_L1 (VGPR cap 32->~85).
// Theory: k_L0 runs ~1940 VALU instr/thread vs ~900 essential (69us x 75%
// VALUBusy / 32 waves/SIMD-pass); VGPR=32 forces address/constant remat.
// Prediction: VGPR_Count -> 60-85, k_L0 < 66us, total 212-222. If k_L0 in
// 69-77 noise band or VGPR stays low -> falsified, pure revert next.
// DEAD BRANCHES (counter-verified, do not retry):
//  - R15/16+R22: ANY cross-block coherence tail (threadfence OR relaxed
//    device-scope atomics OR agent loads at scale) -> he0g residency destroyed
//    (FETCH 10->46MB signature), k_L1 +36..+280us. Kills spin-wait fusion too.
//  - R19: intra-phase VALU trimming (scalar->b128 stores, p-transpose): dur flat.
//  - R20: tail algebra + tB double-buffer: LDS 21KB -> occupancy 8->7, +2us;
//    extra k_pre work regressed hidden dispatches.
//  - Launch slots cost ~14us each (R19 +1 launch = +14.6 with k_L0 flat).
// Container noise: +-7% per kernel on identical source.
// Merged weights: SA=ew2@w1he0, SB=w2_0@u1_0(+biasB), SC=w2_0@w1he1, SD=w2_1@u1_1(+biasD);
// p0' carries b1_0+eb2@w1he0; p1' carries b1n+b2_0@w1he1 (biasC).
// MFMA fragment addressing identical to R9-R14 (verified).

typedef unsigned short u16;
typedef unsigned int u32;
typedef _Float16 half8 __attribute__((ext_vector_type(8)));   // 4 VGPR frag
typedef __attribute__((ext_vector_type(4))) float floatx4;

#define TS 72            // LDS tile row stride (f16): 144 B
#define HROW 72          // he0g row stride (u16) — mirrors LDS tile
#define HBLK (64 * HROW) // 4608 u16 per block

// gelu via A&S 7.1.27 rational erf (|eps|<=5e-4), no exp (R14-verified)
__device__ __forceinline__ float gelu_f(float x) {
    float s = fabsf(x) * 0.70710678118654752f;
    float q = fmaf(fmaf(fmaf(fmaf(0.078108f, s, 0.000972f), s, 0.230389f), s, 0.278393f), s, 1.0f);
    float q2 = q * q;
    float r = __builtin_amdgcn_rcpf(q2 * q2);
    float t = 0.5f * x * r;
    return x > 0.f ? x - t : t;
}

// k_pre: blocks [0,64): 4 merged 64x64 products -> WF f16 frag layout;
//        block 64: bias vectors; blocks [65,129): 4 f32 transposes;
//        blocks [129,2177): node MLP + p0' (biasA fold inline), 4 nodes/block.
__global__ __launch_bounds__(256) void k_pre(
    const float* __restrict__ ew2, const float* __restrict__ w1he0,
    const float* __restrict__ w2_0, const float* __restrict__ u1_0,
    const float* __restrict__ w1he1, const float* __restrict__ w2_1,
    const float* __restrict__ u1_1,
    const float* __restrict__ eb2, const float* __restrict__ b2_0,
    const float* __restrict__ c1_0, const float* __restrict__ b2_1,
    const float* __restrict__ c1_1,
    const float* __restrict__ b1_0v, const float* __restrict__ b1nv,
    const float* __restrict__ u2_0, const float* __restrict__ u2_1,
    const float* __restrict__ w1n, const float* __restrict__ hw1,
    _Float16* __restrict__ WF,
    float* __restrict__ biasB, float* __restrict__ biasC, float* __restrict__ biasD,
    float* __restrict__ u2_0T, float* __restrict__ u2_1T,
    float* __restrict__ w1nT, float* __restrict__ hw1T,
    const float* __restrict__ x, const float* __restrict__ spin,
    const float* __restrict__ nw1, const float* __restrict__ nb1,
    const float* __restrict__ nw2, const float* __restrict__ nb2,
    const float* __restrict__ w1_0,
    float* __restrict__ hv, float* __restrict__ p0)
{
    int blk = blockIdx.x;
    if (blk < 64) {
        int s = blk >> 4;                               // product id
        int idx = (blk & 15) * 256 + threadIdx.x;       // 0..4095
        int k = idx >> 6, n = idx & 63;
        const float *A, *Bm;
        if (s == 0)      { A = ew2;  Bm = w1he0; }
        else if (s == 1) { A = w2_0; Bm = u1_0;  }
        else if (s == 2) { A = w2_0; Bm = w1he1; }
        else             { A = w2_1; Bm = u1_1;  }
        float acc = 0.f;
        for (int q = 0; q < 64; ++q) acc = fmaf(A[k * 64 + q], Bm[q * 64 + n], acc);
        int kc = k >> 5, qd = (k >> 3) & 3, jj = k & 7;
        WF[(((s * 2 + kc) * 64 + n) * 4 + qd) * 8 + jj] = (_Float16)acc;
    } else if (blk == 64) {
        int s = threadIdx.x >> 6, cc = threadIdx.x & 63;
        if (s > 0) {
            const float *bv, *Bm, *add; float* dst;
            if (s == 1)      { bv = b2_0; Bm = u1_0;  add = c1_0; dst = biasB; }
            else if (s == 2) { bv = b2_0; Bm = w1he1; add = b1nv; dst = biasC; }
            else             { bv = b2_1; Bm = u1_1;  add = c1_1; dst = biasD; }
            float acc = add[cc];
            for (int q = 0; q < 64; ++q) acc = fmaf(bv[q], Bm[q * 64 + cc], acc);
            dst[cc] = acc;
        }
    } else if (blk < 129) {
        int idx = (blk - 65) * 256 + threadIdx.x;       // 0..16383
        int s = idx >> 12, r = idx & 4095, m = r >> 6, tc = r & 63;
        const float* W = s == 0 ? u2_0 : s == 1 ? u2_1 : s == 2 ? w1n : hw1;
        float* WT      = s == 0 ? u2_0T : s == 1 ? u2_1T : s == 2 ? w1nT : hw1T;
        WT[tc * 64 + m] = W[m * 64 + tc];
    } else {
        __shared__ float a[4][64];
        __shared__ float shv[4][64];
        int w = threadIdx.x >> 6, h = threadIdx.x & 63;
        int node = (blk - 129) * 4 + w;
        float2 xv = ((const float2*)x)[node];
        float sp = spin[node];
        float z = fmaf(xv.x, nw1[h], fmaf(xv.y, nw1[64 + h], fmaf(sp, nw1[128 + h], nb1[h])));
        a[w][h] = gelu_f(z);                         // wave-synchronous slice
        float acc = nb2[h];
        for (int k = 0; k < 64; ++k) acc = fmaf(a[w][k], nw2[k * 64 + h], acc);
        hv[node * 64 + h] = acc;
        shv[w][h] = acc;
        // p0' = b1_0 + eb2@w1he0 (biasA fold, inline) + hv@w1_0
        float pa = b1_0v[h];
        for (int q = 0; q < 64; ++q) pa = fmaf(eb2[q], w1he0[q * 64 + h], pa);
        for (int k = 0; k < 64; ++k) pa = fmaf(shv[w][k], w1_0[k * 64 + h], pa);
        p0[node * 64 + h] = pa;
    }
}

// accumulate one 64x64 stage into pre-initialized acc; A from LDS (R9-verified)
__device__ __forceinline__ void mfma_acc(
    const _Float16* __restrict__ tA, const _Float16* __restrict__ WF,
    int stage, int c, int quad, int nn, floatx4 acc[4])
{
    int sA = ((nn >> 2) & 3) << 3;
    #pragma unroll
    for (int kc = 0; kc < 2; ++kc) {
        half8 bf = *(const half8*)(WF + (((stage * 2 + kc) * 64 + c) * 4 + quad) * 8);
        int k0 = (kc * 32 + quad * 8) ^ sA;
        #pragma unroll
        for (int mt = 0; mt < 4; ++mt) {
            half8 af = *(const half8*)(tA + (mt * 16 + nn) * TS + k0);
            acc[mt] = __builtin_amdgcn_mfma_f32_16x16x32_f16(af, bf, acc[mt], 0, 0, 0);
        }
    }
}

__device__ __forceinline__ void init_bias(floatx4 acc[4], float bc) {
    #pragma unroll
    for (int mt = 0; mt < 4; ++mt) acc[mt] = (floatx4){bc, bc, bc, bc};
}
__device__ __forceinline__ void init_p(floatx4 acc[4], const float* __restrict__ p,
                                       int rowbase, int c, int quad) {
    #pragma unroll
    for (int mt = 0; mt < 4; ++mt)
        #pragma unroll
        for (int r = 0; r < 4; ++r)
            acc[mt][r] = p[(rowbase + mt * 16 + quad * 4 + r) * 64 + c];
}

__global__ __launch_bounds__(256, 6) void k_L0(
    const float* __restrict__ x,
    const float* __restrict__ ew1, const float* __restrict__ eb1,
    const float* __restrict__ p0,        // p0' (biasA folded)
    const float* __restrict__ biasB,
    const float* __restrict__ u2_0T, const float* __restrict__ c2_0,
    const _Float16* __restrict__ WF,
    const float* __restrict__ hv0, float* __restrict__ hv1,
    const float* __restrict__ w1nT, const float* __restrict__ biasC,
    float* __restrict__ p1,
    u16* __restrict__ he0g)
{
    __shared__ __align__(16) _Float16 tA[64 * TS];
    __shared__ float sS[64];
    __shared__ float shv[64];
    __shared__ float sred[256];
    int t = threadIdx.x, L = t & 63;
    int w = __builtin_amdgcn_readfirstlane(t >> 6);
    int nn = L & 15, quad = L >> 4;
    int c = w * 16 + nn;
    int cw = c ^ (quad << 3);
    int b = blockIdx.x >> 6, j = blockIdx.x & 63;

    // geometry in registers: lane = i = L
    float2 xi = ((const float2*)x)[b * 64 + L];
    float2 xj = ((const float2*)x)[b * 64 + j];
    float d0 = xj.x - xi.x, d1 = xj.y - xi.y;     // dr = x_j - x_i
    float r2 = fmaf(d0, d0, d1 * d1);
    float rr = sqrtf(r2 + 1e-12f);
    int swL = ((L >> 2) & 3) << 3;

    // g1 row L, m in [w*16, w*16+16): SGPR weights, packed b128 writes
    #pragma unroll
    for (int mb = 0; mb < 2; ++mb) {
        int m0 = w * 16 + mb * 8;
        half8 h8;
        #pragma unroll
        for (int kk = 0; kk < 8; ++kk) {
            int m = m0 + kk;
            float z = fmaf(d0, ew1[m], fmaf(d1, ew1[64 + m],
                      fmaf(rr, ew1[128 + m], fmaf(r2, ew1[192 + m], eb1[m]))));
            h8[kk] = (_Float16)gelu_f(z);
        }
        *(half8*)(tA + L * TS + (m0 ^ swL)) = h8;
    }
    __syncthreads();

    floatx4 acc[4];
    // M1: z0 = p0' + g1 @ SA -> Y = gelu; store Y to LDS + he0g (row stride 72)
    init_p(acc, p0, b * 64, c, quad);
    mfma_acc(tA, WF, 0, c, quad, nn, acc);
    __syncthreads();
    {
        u16* dst = he0g + (size_t)blockIdx.x * HBLK;
        #pragma unroll
        for (int mt = 0; mt < 4; ++mt)
            #pragma unroll
            for (int r = 0; r < 4; ++r) {
                int i = mt * 16 + quad * 4 + r;
                _Float16 y = (_Float16)gelu_f(acc[mt][r]);
                tA[i * TS + cw] = y;
                dst[i * HROW + cw] = __builtin_bit_cast(u16, y);
            }
    }
    __syncthreads();
    // M2: a = gelu(Y @ SB + biasB); masked i-sum -> sS
    init_bias(acc, biasB[c]);
    mfma_acc(tA, WF, 1, c, quad, nn, acc);
    {
        float s = 0.f;
        #pragma unroll
        for (int mt = 0; mt < 4; ++mt)
            #pragma unroll
            for (int r = 0; r < 4; ++r) {
                int i = mt * 16 + quad * 4 + r;
                float g = gelu_f(acc[mt][r]);
                s += (i == j) ? 0.f : g;
            }
        s += __shfl_xor(s, 16);
        s += __shfl_xor(s, 32);
        if (quad == 0) sS[c] = s;
    }
    __syncthreads();
    // tail phase A: hv1 (parallel over 256)
    {
        const float4* sv4 = (const float4*)(sS + w * 16);
        const float4* uv4 = (const float4*)(u2_0T + L * 64 + w * 16);
        float g = 0.f;
        #pragma unroll
        for (int m4 = 0; m4 < 4; ++m4) {
            float4 sv = sv4[m4], uv = uv4[m4];
            g = fmaf(sv.x, uv.x, fmaf(sv.y, uv.y, fmaf(sv.z, uv.z, fmaf(sv.w, uv.w, g))));
        }
        sred[w * 64 + L] = g;
    }
    __syncthreads();
    if (t < 64) {
        float g = sred[t] + sred[64 + t] + sred[128 + t] + sred[192 + t];
        int o = blockIdx.x * 64 + t;
        float hvv = hv0[o] + g * (1.0f / 63.0f) + c2_0[t];
        hv1[o] = hvv;
        shv[t] = hvv;
    }
    __syncthreads();
    // tail phase B: p1' (parallel over 256)
    {
        const float4* hv4 = (const float4*)(shv + w * 16);
        const float4* wv4 = (const float4*)(w1nT + L * 64 + w * 16);
        float pa = 0.f;
        #pragma unroll
        for (int m4 = 0; m4 < 4; ++m4) {
            float4 sv = hv4[m4], uv = wv4[m4];
            pa = fmaf(sv.x, uv.x, fmaf(sv.y, uv.y, fmaf(sv.z, uv.z, fmaf(sv.w, uv.w, pa))));
        }
        sred[w * 64 + L] = pa;
    }
    __syncthreads();
    if (t < 64)
        p1[blockIdx.x * 64 + t] = biasC[t] + sred[t] + sred[64 + t] + sred[128 + t] + sred[192 + t];
}

__global__ __launch_bounds__(256, 6) void k_L1(
    const u16* __restrict__ he0g,
    const float* __restrict__ p1,        // p1' (biasC folded)
    const float* __restrict__ biasD,
    const float* __restrict__ u2_1T, const float* __restrict__ c2_1,
    const _Float16* __restrict__ WF,
    const float* __restrict__ hv1,
    const float* __restrict__ hw1T, const float* __restrict__ hb1,
    const float* __restrict__ hw2, const float* __restrict__ hb2,
    const float* __restrict__ scale, float* __restrict__ dx)
{
    __shared__ __align__(16) _Float16 tA[64 * TS];
    __shared__ float sS[64];
    __shared__ float shv[64];
    __shared__ float sred[256];
    int t = threadIdx.x, L = t & 63;
    int w = __builtin_amdgcn_readfirstlane(t >> 6);
    int nn = L & 15, quad = L >> 4;
    int c = w * 16 + nn;
    int cw = c ^ (quad << 3);
    int b = blockIdx.x >> 6, j = blockIdx.x & 63;

    {   // Y load: he0g layout mirrors LDS tile exactly -> linear float4 copy
        const float4* src = (const float4*)(he0g + (size_t)blockIdx.x * HBLK);
        float4* dstl = (float4*)tA;
        for (int q = t; q < (HBLK * 2 / 16); q += 256)   // 576 chunks
            dstl[q] = src[q];
    }
    __syncthreads();

    floatx4 acc[4];
    // M3: z1 = p1' + Y @ SC -> Y2 = gelu
    init_p(acc, p1, b * 64, c, quad);
    mfma_acc(tA, WF, 2, c, quad, nn, acc);
    __syncthreads();
    #pragma unroll
    for (int mt = 0; mt < 4; ++mt)
        #pragma unroll
        for (int r = 0; r < 4; ++r)
            tA[(mt * 16 + quad * 4 + r) * TS + cw] = (_Float16)gelu_f(acc[mt][r]);
    __syncthreads();
    // M4: a = gelu(Y2 @ SD + biasD); masked i-sum -> sS
    init_bias(acc, biasD[c]);
    mfma_acc(tA, WF, 3, c, quad, nn, acc);
    {
        float s = 0.f;
        #pragma unroll
        for (int mt = 0; mt < 4; ++mt)
            #pragma unroll
            for (int r = 0; r < 4; ++r) {
                int i = mt * 16 + quad * 4 + r;
                float g = gelu_f(acc[mt][r]);
                s += (i == j) ? 0.f : g;
            }
        s += __shfl_xor(s, 16);
        s += __shfl_xor(s, 32);
        if (quad == 0) sS[c] = s;
    }
    __syncthreads();
    // tail phase A: hv2
    {
        const float4* sv4 = (const float4*)(sS + w * 16);
        const float4* uv4 = (const float4*)(u2_1T + L * 64 + w * 16);
        float g = 0.f;
        #pragma unroll
        for (int m4 = 0; m4 < 4; ++m4) {
            float4 sv = sv4[m4], uv = uv4[m4];
            g = fmaf(sv.x, uv.x, fmaf(sv.y, uv.y, fmaf(sv.z, uv.z, fmaf(sv.w, uv.w, g))));
        }
        sred[w * 64 + L] = g;
    }
    __syncthreads();
    if (t < 64) {
        float g = sred[t] + sred[64 + t] + sred[128 + t] + sred[192 + t];
        float hv2 = hv1[blockIdx.x * 64 + t] + g * (1.0f / 63.0f) + c2_1[t];
        shv[t] = hv2;
    }
    __syncthreads();
    // tail phase B: head layer-1 (parallel) -> tanh
    {
        const float4* hv4 = (const float4*)(shv + w * 16);
        const float4* wv4 = (const float4*)(hw1T + L * 64 + w * 16);
        float a = 0.f;
        #pragma unroll
        for (int m4 = 0; m4 < 4; ++m4) {
            float4 sv = hv4[m4], uv = wv4[m4];
            a = fmaf(sv.x, uv.x, fmaf(sv.y, uv.y, fmaf(sv.z, uv.z, fmaf(sv.w, uv.w, a))));
        }
        sred[w * 64 + L] = a;
    }
    __syncthreads();
    if (t < 64) {
        float a = hb1[t] + sred[t] + sred[64 + t] + sred[128 + t] + sred[192 + t];
        float t1 = tanhf(a);
        float dd0 = t1 * hw2[t * 2], dd1 = t1 * hw2[t * 2 + 1];
        #pragma unroll
        for (int off = 1; off <= 32; off <<= 1) { dd0 += __shfl_xor(dd0, off); dd1 += __shfl_xor(dd1, off); }
        if (t == 0) {
            float sp = log1pf(__expf(scale[0]));
            dx[blockIdx.x * 2 + 0] = (dd0 + hb2[0]) * sp;
            dx[blockIdx.x * 2 + 1] = (dd1 + hb2[1]) * sp;
        }
    }
}

__global__ __launch_bounds__(64) void k_mean(
    const float* __restrict__ dx, float* __restrict__ out)
{
    __shared__ float s0[64], s1[64];
    int b = blockIdx.x, j = threadIdx.x;
    float2 d = ((const float2*)dx)[b * 64 + j];
    s0[j] = d.x; s1[j] = d.y;
    __syncthreads();
    float m0 = 0.f, m1 = 0.f;
    for (int q = 0; q < 64; ++q) { m0 += s0[q]; m1 += s1[q]; }
    ((float2*)out)[b * 64 + j] = make_float2(d.x - m0 * (1.0f / 64.0f), d.y - m1 * (1.0f / 64.0f));
}

__global__ void k_beacon(float* out, float code) { out[0] = code; }

extern "C" void kernel_launch(void* const* d_in, const int* in_sizes, int n_in,
                              void* d_out, int out_size, void* d_ws, size_t ws_size,
                              hipStream_t stream)
{
    static const int exp_sizes[23] = {
        16384, 8192, 192, 64, 4096, 64,
        256, 64, 4096, 64,
        16384, 128, 8192, 128,
        8192, 128, 8192, 128,
        4096, 64, 128, 2, 1
    };
    // ws layout
    float* hv0 = (float*)d_ws;                  // 524288 f
    float* hv1 = hv0 + 524288;
    float* p0  = hv1 + 524288;
    float* p1  = p0  + 524288;
    float* dx  = p1  + 524288;                  // 16384 f
    float* u2_0T = dx + 16384;                  // 4096 f
    float* u2_1T = u2_0T + 4096;
    float* w1nT  = u2_1T + 4096;
    float* hw1T  = w1nT + 4096;
    float* biasB = hw1T + 4096;                 // 3 x 64 f
    float* biasC = biasB + 64;
    float* biasD = biasC + 64;
    _Float16* WF = (_Float16*)(biasD + 64);     // 16384 f16 (4 stages)
    u16* he0g  = (u16*)(WF + 16384);            // 8192*4608 u16 (75.5 MB)
    const size_t need = (size_t)((char*)(he0g + (size_t)8192 * HBLK) - (char*)d_ws);

    int bad = -1;
    if (n_in != 23 || out_size != 16384) bad = 98;
    else if (ws_size < need) bad = 97;
    else for (int i = 0; i < 23; ++i)
        if (in_sizes[i] != exp_sizes[i]) { bad = i; break; }
    if (bad >= 0) {
        k_beacon<<<1, 1, 0, stream>>>((float*)d_out, 2e6f + bad * 1e4f);
        return;
    }

    const float* x      = (const float*)d_in[0];
    const float* spin   = (const float*)d_in[1];
    const float* nw1    = (const float*)d_in[2];
    const float* nb1    = (const float*)d_in[3];
    const float* nw2    = (const float*)d_in[4];
    const float* nb2    = (const float*)d_in[5];
    const float* ew1    = (const float*)d_in[6];
    const float* eb1    = (const float*)d_in[7];
    const float* ew2    = (const float*)d_in[8];
    const float* eb2    = (const float*)d_in[9];
    const float* v2e_w1 = (const float*)d_in[10];
    const float* v2e_b1 = (const float*)d_in[11];
    const float* v2e_w2 = (const float*)d_in[12];
    const float* v2e_b2 = (const float*)d_in[13];
    const float* e2v_w1 = (const float*)d_in[14];
    const float* e2v_b1 = (const float*)d_in[15];
    const float* e2v_w2 = (const float*)d_in[16];
    const float* e2v_b2 = (const float*)d_in[17];
    const float* hw1    = (const float*)d_in[18];
    const float* hb1    = (const float*)d_in[19];
    const float* hw2    = (const float*)d_in[20];
    const float* hb2    = (const float*)d_in[21];
    const float* scale  = (const float*)d_in[22];

    // layer slices: w1he_l = v2e_w1 + l*8192 + 4096 (edge part); w1n_l = v2e_w1 + l*8192
    k_pre<<<2177, 256, 0, stream>>>(
        ew2, v2e_w1 + 4096, v2e_w2, e2v_w1,
        v2e_w1 + 12288, v2e_w2 + 4096, e2v_w1 + 4096,
        eb2, v2e_b2, e2v_b1, v2e_b2 + 64, e2v_b1 + 64,
        v2e_b1, v2e_b1 + 64,
        e2v_w2, e2v_w2 + 4096, v2e_w1 + 8192, hw1,
        WF, biasB, biasC, biasD,
        u2_0T, u2_1T, w1nT, hw1T,
        x, spin, nw1, nb1, nw2, nb2, v2e_w1, hv0, p0);
    k_L0<<<8192, 256, 0, stream>>>(x, ew1, eb1,
        p0, biasB, u2_0T, e2v_b2,
        WF, hv0, hv1,
        w1nT, biasC, p1,
        he0g);
    k_L1<<<8192, 256, 0, stream>>>(he0g,
        p1, biasD, u2_1T, e2v_b2 + 64,
        WF, hv1, hw1T, hb1, hw2, hb2, scale, dx);
    k_mean<<<128, 64, 0, stream>>>(dx, (float*)d_out);
}

// Round 7
// 212.141 us; speedup vs baseline: 1.2397x; 1.1052x over previous
//
#include <hip/hip_runtime.h>
#include <math.h>

// B=128, N=64, D=2, H=64, M=64, L=2. f32 in / f32 out.
// R24 = R21 structure with k_L0/k_L1 processing TWO j's per block (grid 4096).
// Theory: per-block time is pinned by the serial phase chain (7 barriers,
// LDS<->MFMA<->gelu deps), not marginal VALU (R19: trim -> flat) and not
// registers (R23: cap lifted, compiler stayed at 32 VGPR). Amortize the chain:
// 2 j's share p0 rows, WF B-frags, bias loads, tail weight columns, ew1; VALU
// ~1.7x/thread but waves halve (net 0.85x) and barriers-per-j halve. LDS 21.5KB
// -> 7 blk/CU (R20 measured that cost at ~+2us; amortization should net more).
// Prediction: k_L0 70->58-64, k_L1 -8-10, total ~212-220. If k_L0 >= 68 ->
// theory dead, revert to R21 and declare structural ceiling.
// DEAD BRANCHES (counter-verified): cross-block coherence tails (R15/16/R22:
// FETCH 10->46MB he0g poison); intra-phase VALU trimming (R19 flat); tail
// algebra + dbuf (R20); VGPR-cap theory (R23: compiler chooses 32).
// Launch slots ~14us each; container noise +-7%/kernel.
// Merged weights: SA=ew2@w1he0, SB=w2_0@u1_0(+biasB), SC=w2_0@w1he1, SD=w2_1@u1_1(+biasD);
// p0' carries b1_0+eb2@w1he0; p1' carries b1n+b2_0@w1he1 (biasC).
// MFMA fragment addressing identical to R9-R14 (verified).

typedef unsigned short u16;
typedef unsigned int u32;
typedef _Float16 half8 __attribute__((ext_vector_type(8)));   // 4 VGPR frag
typedef __attribute__((ext_vector_type(4))) float floatx4;

#define TS 72            // LDS tile row stride (f16): 144 B
#define HROW 72          // he0g row stride (u16) — mirrors LDS tile
#define HBLK (64 * HROW) // 4608 u16 per (b,j) tile

// gelu via A&S 7.1.27 rational erf (|eps|<=5e-4), no exp (R14-verified)
__device__ __forceinline__ float gelu_f(float x) {
    float s = fabsf(x) * 0.70710678118654752f;
    float q = fmaf(fmaf(fmaf(fmaf(0.078108f, s, 0.000972f), s, 0.230389f), s, 0.278393f), s, 1.0f);
    float q2 = q * q;
    float r = __builtin_amdgcn_rcpf(q2 * q2);
    float t = 0.5f * x * r;
    return x > 0.f ? x - t : t;
}

// k_pre: unchanged from R21 (verified).
__global__ __launch_bounds__(256) void k_pre(
    const float* __restrict__ ew2, const float* __restrict__ w1he0,
    const float* __restrict__ w2_0, const float* __restrict__ u1_0,
    const float* __restrict__ w1he1, const float* __restrict__ w2_1,
    const float* __restrict__ u1_1,
    const float* __restrict__ eb2, const float* __restrict__ b2_0,
    const float* __restrict__ c1_0, const float* __restrict__ b2_1,
    const float* __restrict__ c1_1,
    const float* __restrict__ b1_0v, const float* __restrict__ b1nv,
    const float* __restrict__ u2_0, const float* __restrict__ u2_1,
    const float* __restrict__ w1n, const float* __restrict__ hw1,
    _Float16* __restrict__ WF,
    float* __restrict__ biasB, float* __restrict__ biasC, float* __restrict__ biasD,
    float* __restrict__ u2_0T, float* __restrict__ u2_1T,
    float* __restrict__ w1nT, float* __restrict__ hw1T,
    const float* __restrict__ x, const float* __restrict__ spin,
    const float* __restrict__ nw1, const float* __restrict__ nb1,
    const float* __restrict__ nw2, const float* __restrict__ nb2,
    const float* __restrict__ w1_0,
    float* __restrict__ hv, float* __restrict__ p0)
{
    int blk = blockIdx.x;
    if (blk < 64) {
        int s = blk >> 4;                               // product id
        int idx = (blk & 15) * 256 + threadIdx.x;       // 0..4095
        int k = idx >> 6, n = idx & 63;
        const float *A, *Bm;
        if (s == 0)      { A = ew2;  Bm = w1he0; }
        else if (s == 1) { A = w2_0; Bm = u1_0;  }
        else if (s == 2) { A = w2_0; Bm = w1he1; }
        else             { A = w2_1; Bm = u1_1;  }
        float acc = 0.f;
        for (int q = 0; q < 64; ++q) acc = fmaf(A[k * 64 + q], Bm[q * 64 + n], acc);
        int kc = k >> 5, qd = (k >> 3) & 3, jj = k & 7;
        WF[(((s * 2 + kc) * 64 + n) * 4 + qd) * 8 + jj] = (_Float16)acc;
    } else if (blk == 64) {
        int s = threadIdx.x >> 6, cc = threadIdx.x & 63;
        if (s > 0) {
            const float *bv, *Bm, *add; float* dst;
            if (s == 1)      { bv = b2_0; Bm = u1_0;  add = c1_0; dst = biasB; }
            else if (s == 2) { bv = b2_0; Bm = w1he1; add = b1nv; dst = biasC; }
            else             { bv = b2_1; Bm = u1_1;  add = c1_1; dst = biasD; }
            float acc = add[cc];
            for (int q = 0; q < 64; ++q) acc = fmaf(bv[q], Bm[q * 64 + cc], acc);
            dst[cc] = acc;
        }
    } else if (blk < 129) {
        int idx = (blk - 65) * 256 + threadIdx.x;       // 0..16383
        int s = idx >> 12, r = idx & 4095, m = r >> 6, tc = r & 63;
        const float* W = s == 0 ? u2_0 : s == 1 ? u2_1 : s == 2 ? w1n : hw1;
        float* WT      = s == 0 ? u2_0T : s == 1 ? u2_1T : s == 2 ? w1nT : hw1T;
        WT[tc * 64 + m] = W[m * 64 + tc];
    } else {
        __shared__ float a[4][64];
        __shared__ float shv[4][64];
        int w = threadIdx.x >> 6, h = threadIdx.x & 63;
        int node = (blk - 129) * 4 + w;
        float2 xv = ((const float2*)x)[node];
        float sp = spin[node];
        float z = fmaf(xv.x, nw1[h], fmaf(xv.y, nw1[64 + h], fmaf(sp, nw1[128 + h], nb1[h])));
        a[w][h] = gelu_f(z);                         // wave-synchronous slice
        float acc = nb2[h];
        for (int k = 0; k < 64; ++k) acc = fmaf(a[w][k], nw2[k * 64 + h], acc);
        hv[node * 64 + h] = acc;
        shv[w][h] = acc;
        // p0' = b1_0 + eb2@w1he0 (biasA fold, inline) + hv@w1_0
        float pa = b1_0v[h];
        for (int q = 0; q < 64; ++q) pa = fmaf(eb2[q], w1he0[q * 64 + h], pa);
        for (int k = 0; k < 64; ++k) pa = fmaf(shv[w][k], w1_0[k * 64 + h], pa);
        p0[node * 64 + h] = pa;
    }
}

// dual-tile MFMA: shared B-fragment, two A-tiles (R9-verified addressing)
__device__ __forceinline__ void mfma_acc2(
    const _Float16* __restrict__ tA0, const _Float16* __restrict__ tA1,
    const _Float16* __restrict__ WF,
    int stage, int c, int quad, int nn, floatx4 acc0[4], floatx4 acc1[4])
{
    int sA = ((nn >> 2) & 3) << 3;
    #pragma unroll
    for (int kc = 0; kc < 2; ++kc) {
        half8 bf = *(const half8*)(WF + (((stage * 2 + kc) * 64 + c) * 4 + quad) * 8);
        int k0 = (kc * 32 + quad * 8) ^ sA;
        #pragma unroll
        for (int mt = 0; mt < 4; ++mt) {
            half8 af0 = *(const half8*)(tA0 + (mt * 16 + nn) * TS + k0);
            half8 af1 = *(const half8*)(tA1 + (mt * 16 + nn) * TS + k0);
            acc0[mt] = __builtin_amdgcn_mfma_f32_16x16x32_f16(af0, bf, acc0[mt], 0, 0, 0);
            acc1[mt] = __builtin_amdgcn_mfma_f32_16x16x32_f16(af1, bf, acc1[mt], 0, 0, 0);
        }
    }
}

__device__ __forceinline__ void init_bias(floatx4 acc[4], float bc) {
    #pragma unroll
    for (int mt = 0; mt < 4; ++mt) acc[mt] = (floatx4){bc, bc, bc, bc};
}
__device__ __forceinline__ void init_p(floatx4 acc[4], const float* __restrict__ p,
                                       int rowbase, int c, int quad) {
    #pragma unroll
    for (int mt = 0; mt < 4; ++mt)
        #pragma unroll
        for (int r = 0; r < 4; ++r)
            acc[mt][r] = p[(rowbase + mt * 16 + quad * 4 + r) * 64 + c];
}

__global__ __launch_bounds__(256, 4) void k_L0(
    const float* __restrict__ x,
    const float* __restrict__ ew1, const float* __restrict__ eb1,
    const float* __restrict__ p0,        // p0' (biasA folded), per (b,i)
    const float* __restrict__ biasB,
    const float* __restrict__ u2_0T, const float* __restrict__ c2_0,
    const _Float16* __restrict__ WF,
    const float* __restrict__ hv0, float* __restrict__ hv1,
    const float* __restrict__ w1nT, const float* __restrict__ biasC,
    float* __restrict__ p1,
    u16* __restrict__ he0g)
{
    __shared__ __align__(16) _Float16 tA0[64 * TS];
    __shared__ __align__(16) _Float16 tA1[64 * TS];
    __shared__ float sS0[64], sS1[64];
    __shared__ float shv[2][64];
    __shared__ float sredA[256], sredB[256];
    int t = threadIdx.x, L = t & 63;
    int w = __builtin_amdgcn_readfirstlane(t >> 6);
    int nn = L & 15, quad = L >> 4;
    int c = w * 16 + nn;
    int cw = c ^ (quad << 3);
    int b = blockIdx.x >> 5, jp = blockIdx.x & 31;
    int j0 = jp * 2, j1 = j0 + 1;

    // geometry: lane = i = L; two destinations j0, j1
    float2 xi = ((const float2*)x)[b * 64 + L];
    float2 xa = ((const float2*)x)[b * 64 + j0];
    float2 xb = ((const float2*)x)[b * 64 + j1];
    float da0 = xa.x - xi.x, da1 = xa.y - xi.y;
    float r2a = fmaf(da0, da0, da1 * da1);
    float rra = sqrtf(r2a + 1e-12f);
    float db0 = xb.x - xi.x, db1 = xb.y - xi.y;
    float r2b = fmaf(db0, db0, db1 * db1);
    float rrb = sqrtf(r2b + 1e-12f);
    int swL = ((L >> 2) & 3) << 3;

    // g1 rows for both j (ew1/eb1 SGPR loads shared)
    #pragma unroll
    for (int mb = 0; mb < 2; ++mb) {
        int m0 = w * 16 + mb * 8;
        half8 h8a, h8b;
        #pragma unroll
        for (int kk = 0; kk < 8; ++kk) {
            int m = m0 + kk;
            float e0 = ew1[m], e1 = ew1[64 + m], e2 = ew1[128 + m], e3 = ew1[192 + m], e4 = eb1[m];
            float za = fmaf(da0, e0, fmaf(da1, e1, fmaf(rra, e2, fmaf(r2a, e3, e4))));
            float zb = fmaf(db0, e0, fmaf(db1, e1, fmaf(rrb, e2, fmaf(r2b, e3, e4))));
            h8a[kk] = (_Float16)gelu_f(za);
            h8b[kk] = (_Float16)gelu_f(zb);
        }
        *(half8*)(tA0 + L * TS + (m0 ^ swL)) = h8a;
        *(half8*)(tA1 + L * TS + (m0 ^ swL)) = h8b;
    }
    __syncthreads();                                  // (1) g1 ready

    floatx4 acc0[4], acc1[4];
    // M1: z0 = p0' + g1 @ SA (p0 rows shared across j)
    init_p(acc0, p0, b * 64, c, quad);
    #pragma unroll
    for (int mt = 0; mt < 4; ++mt) acc1[mt] = acc0[mt];
    mfma_acc2(tA0, tA1, WF, 0, c, quad, nn, acc0, acc1);
    __syncthreads();                                  // (2) tA reads done
    {
        u16* dst0 = he0g + (size_t)(b * 64 + j0) * HBLK;
        u16* dst1 = he0g + (size_t)(b * 64 + j1) * HBLK;
        #pragma unroll
        for (int mt = 0; mt < 4; ++mt)
            #pragma unroll
            for (int r = 0; r < 4; ++r) {
                int i = mt * 16 + quad * 4 + r;
                _Float16 ya = (_Float16)gelu_f(acc0[mt][r]);
                _Float16 yb = (_Float16)gelu_f(acc1[mt][r]);
                tA0[i * TS + cw] = ya;
                tA1[i * TS + cw] = yb;
                dst0[i * HROW + cw] = __builtin_bit_cast(u16, ya);
                dst1[i * HROW + cw] = __builtin_bit_cast(u16, yb);
            }
    }
    __syncthreads();                                  // (3) Y visible
    // M2: a = gelu(Y @ SB + biasB); masked i-sums
    {
        float bb = biasB[c];
        init_bias(acc0, bb);
        init_bias(acc1, bb);
    }
    mfma_acc2(tA0, tA1, WF, 1, c, quad, nn, acc0, acc1);
    {
        float s0 = 0.f, s1 = 0.f;
        #pragma unroll
        for (int mt = 0; mt < 4; ++mt)
            #pragma unroll
            for (int r = 0; r < 4; ++r) {
                int i = mt * 16 + quad * 4 + r;
                float ga = gelu_f(acc0[mt][r]);
                float gb = gelu_f(acc1[mt][r]);
                s0 += (i == j0) ? 0.f : ga;
                s1 += (i == j1) ? 0.f : gb;
            }
        s0 += __shfl_xor(s0, 16); s0 += __shfl_xor(s0, 32);
        s1 += __shfl_xor(s1, 16); s1 += __shfl_xor(s1, 32);
        if (quad == 0) { sS0[c] = s0; sS1[c] = s1; }
    }
    __syncthreads();                                  // (4) sS ready
    // tail A: hv1 aggregation dots, u2_0T columns shared
    {
        const float4* sv0 = (const float4*)(sS0 + w * 16);
        const float4* sv1 = (const float4*)(sS1 + w * 16);
        const float4* uv4 = (const float4*)(u2_0T + L * 64 + w * 16);
        float g0 = 0.f, g1 = 0.f;
        #pragma unroll
        for (int m4 = 0; m4 < 4; ++m4) {
            float4 uv = uv4[m4], a0 = sv0[m4], a1 = sv1[m4];
            g0 = fmaf(a0.x, uv.x, fmaf(a0.y, uv.y, fmaf(a0.z, uv.z, fmaf(a0.w, uv.w, g0))));
            g1 = fmaf(a1.x, uv.x, fmaf(a1.y, uv.y, fmaf(a1.z, uv.z, fmaf(a1.w, uv.w, g1))));
        }
        sredA[w * 64 + L] = g0;
        sredB[w * 64 + L] = g1;
    }
    __syncthreads();                                  // (5) sred ready
    if (t < 128) {
        int h = t & 63, sj = t >> 6;
        const float* sr = sj ? sredB : sredA;
        float g = sr[h] + sr[64 + h] + sr[128 + h] + sr[192 + h];
        int jj = sj ? j1 : j0;
        int o = (b * 64 + jj) * 64 + h;
        float hvv = hv0[o] + g * (1.0f / 63.0f) + c2_0[h];
        hv1[o] = hvv;
        shv[sj][h] = hvv;
    }
    __syncthreads();                                  // (6) shv ready
    // tail B: p1' dots, w1nT columns shared
    {
        const float4* h0 = (const float4*)(shv[0] + w * 16);
        const float4* h1 = (const float4*)(shv[1] + w * 16);
        const float4* wv4 = (const float4*)(w1nT + L * 64 + w * 16);
        float pa = 0.f, pb = 0.f;
        #pragma unroll
        for (int m4 = 0; m4 < 4; ++m4) {
            float4 wv = wv4[m4], a0 = h0[m4], a1 = h1[m4];
            pa = fmaf(a0.x, wv.x, fmaf(a0.y, wv.y, fmaf(a0.z, wv.z, fmaf(a0.w, wv.w, pa))));
            pb = fmaf(a1.x, wv.x, fmaf(a1.y, wv.y, fmaf(a1.z, wv.z, fmaf(a1.w, wv.w, pb))));
        }
        sredA[w * 64 + L] = pa;
        sredB[w * 64 + L] = pb;
    }
    __syncthreads();                                  // (7) sred ready
    if (t < 128) {
        int h = t & 63, sj = t >> 6;
        const float* sr = sj ? sredB : sredA;
        int jj = sj ? j1 : j0;
        p1[(b * 64 + jj) * 64 + h] = biasC[h] + sr[h] + sr[64 + h] + sr[128 + h] + sr[192 + h];
    }
}

__global__ __launch_bounds__(256, 4) void k_L1(
    const u16* __restrict__ he0g,
    const float* __restrict__ p1,        // p1' (biasC folded), per (b,i)
    const float* __restrict__ biasD,
    const float* __restrict__ u2_1T, const float* __restrict__ c2_1,
    const _Float16* __restrict__ WF,
    const float* __restrict__ hv1,
    const float* __restrict__ hw1T, const float* __restrict__ hb1,
    const float* __restrict__ hw2, const float* __restrict__ hb2,
    const float* __restrict__ scale, float* __restrict__ dx)
{
    __shared__ __align__(16) _Float16 tA0[64 * TS];
    __shared__ __align__(16) _Float16 tA1[64 * TS];
    __shared__ float sS0[64], sS1[64];
    __shared__ float shv[2][64];
    __shared__ float sredA[256], sredB[256];
    int t = threadIdx.x, L = t & 63;
    int w = __builtin_amdgcn_readfirstlane(t >> 6);
    int nn = L & 15, quad = L >> 4;
    int c = w * 16 + nn;
    int cw = c ^ (quad << 3);
    int b = blockIdx.x >> 5, jp = blockIdx.x & 31;
    int j0 = jp * 2, j1 = j0 + 1;

    {   // Y load: both tiles, linear float4 copies
        const float4* s0 = (const float4*)(he0g + (size_t)(b * 64 + j0) * HBLK);
        const float4* s1 = (const float4*)(he0g + (size_t)(b * 64 + j1) * HBLK);
        float4* d0 = (float4*)tA0;
        float4* d1 = (float4*)tA1;
        for (int q = t; q < (HBLK * 2 / 16); q += 256) { d0[q] = s0[q]; d1[q] = s1[q]; }
    }
    __syncthreads();                                  // (1) Y ready

    floatx4 acc0[4], acc1[4];
    // M3: z1 = p1' + Y @ SC (p1 rows shared across j)
    init_p(acc0, p1, b * 64, c, quad);
    #pragma unroll
    for (int mt = 0; mt < 4; ++mt) acc1[mt] = acc0[mt];
    mfma_acc2(tA0, tA1, WF, 2, c, quad, nn, acc0, acc1);
    __syncthreads();                                  // (2) tA reads done
    #pragma unroll
    for (int mt = 0; mt < 4; ++mt)
        #pragma unroll
        for (int r = 0; r < 4; ++r) {
            int i = mt * 16 + quad * 4 + r;
            tA0[i * TS + cw] = (_Float16)gelu_f(acc0[mt][r]);
            tA1[i * TS + cw] = (_Float16)gelu_f(acc1[mt][r]);
        }
    __syncthreads();                                  // (3) Y2 visible
    // M4: a = gelu(Y2 @ SD + biasD); masked i-sums
    {
        float bd = biasD[c];
        init_bias(acc0, bd);
        init_bias(acc1, bd);
    }
    mfma_acc2(tA0, tA1, WF, 3, c, quad, nn, acc0, acc1);
    {
        float s0 = 0.f, s1 = 0.f;
        #pragma unroll
        for (int mt = 0; mt < 4; ++mt)
            #pragma unroll
            for (int r = 0; r < 4; ++r) {
                int i = mt * 16 + quad * 4 + r;
                float ga = gelu_f(acc0[mt][r]);
                float gb = gelu_f(acc1[mt][r]);
                s0 += (i == j0) ? 0.f : ga;
                s1 += (i == j1) ? 0.f : gb;
            }
        s0 += __shfl_xor(s0, 16); s0 += __shfl_xor(s0, 32);
        s1 += __shfl_xor(s1, 16); s1 += __shfl_xor(s1, 32);
        if (quad == 0) { sS0[c] = s0; sS1[c] = s1; }
    }
    __syncthreads();                                  // (4) sS ready
    // tail A: hv2 aggregation dots, u2_1T columns shared
    {
        const float4* sv0 = (const float4*)(sS0 + w * 16);
        const float4* sv1 = (const float4*)(sS1 + w * 16);
        const float4* uv4 = (const float4*)(u2_1T + L * 64 + w * 16);
        float g0 = 0.f, g1 = 0.f;
        #pragma unroll
        for (int m4 = 0; m4 < 4; ++m4) {
            float4 uv = uv4[m4], a0 = sv0[m4], a1 = sv1[m4];
            g0 = fmaf(a0.x, uv.x, fmaf(a0.y, uv.y, fmaf(a0.z, uv.z, fmaf(a0.w, uv.w, g0))));
            g1 = fmaf(a1.x, uv.x, fmaf(a1.y, uv.y, fmaf(a1.z, uv.z, fmaf(a1.w, uv.w, g1))));
        }
        sredA[w * 64 + L] = g0;
        sredB[w * 64 + L] = g1;
    }
    __syncthreads();                                  // (5) sred ready
    if (t < 128) {
        int h = t & 63, sj = t >> 6;
        const float* sr = sj ? sredB : sredA;
        float g = sr[h] + sr[64 + h] + sr[128 + h] + sr[192 + h];
        int jj = sj ? j1 : j0;
        float hv2 = hv1[(b * 64 + jj) * 64 + h] + g * (1.0f / 63.0f) + c2_1[h];
        shv[sj][h] = hv2;
    }
    __syncthreads();                                  // (6) shv ready
    // tail B: head layer-1 dots, hw1T columns shared
    {
        const float4* h0 = (const float4*)(shv[0] + w * 16);
        const float4* h1 = (const float4*)(shv[1] + w * 16);
        const float4* wv4 = (const float4*)(hw1T + L * 64 + w * 16);
        float a0 = 0.f, a1 = 0.f;
        #pragma unroll
        for (int m4 = 0; m4 < 4; ++m4) {
            float4 wv = wv4[m4], v0 = h0[m4], v1 = h1[m4];
            a0 = fmaf(v0.x, wv.x, fmaf(v0.y, wv.y, fmaf(v0.z, wv.z, fmaf(v0.w, wv.w, a0))));
            a1 = fmaf(v1.x, wv.x, fmaf(v1.y, wv.y, fmaf(v1.z, wv.z, fmaf(v1.w, wv.w, a1))));
        }
        sredA[w * 64 + L] = a0;
        sredB[w * 64 + L] = a1;
    }
    __syncthreads();                                  // (7) sred ready
    if (t < 128) {
        int h = t & 63, sj = t >> 6;   // wave 0 -> j0, wave 1 -> j1
        const float* sr = sj ? sredB : sredA;
        float a = hb1[h] + sr[h] + sr[64 + h] + sr[128 + h] + sr[192 + h];
        float t1 = tanhf(a);
        float dd0 = t1 * hw2[h * 2], dd1 = t1 * hw2[h * 2 + 1];
        #pragma unroll
        for (int off = 1; off <= 32; off <<= 1) { dd0 += __shfl_xor(dd0, off); dd1 += __shfl_xor(dd1, off); }
        if (h == 0) {
            int jj = sj ? j1 : j0;
            float sp = log1pf(__expf(scale[0]));
            dx[(b * 64 + jj) * 2 + 0] = (dd0 + hb2[0]) * sp;
            dx[(b * 64 + jj) * 2 + 1] = (dd1 + hb2[1]) * sp;
        }
    }
}

__global__ __launch_bounds__(64) void k_mean(
    const float* __restrict__ dx, float* __restrict__ out)
{
    __shared__ float s0[64], s1[64];
    int b = blockIdx.x, j = threadIdx.x;
    float2 d = ((const float2*)dx)[b * 64 + j];
    s0[j] = d.x; s1[j] = d.y;
    __syncthreads();
    float m0 = 0.f, m1 = 0.f;
    for (int q = 0; q < 64; ++q) { m0 += s0[q]; m1 += s1[q]; }
    ((float2*)out)[b * 64 + j] = make_float2(d.x - m0 * (1.0f / 64.0f), d.y - m1 * (1.0f / 64.0f));
}

__global__ void k_beacon(float* out, float code) { out[0] = code; }

extern "C" void kernel_launch(void* const* d_in, const int* in_sizes, int n_in,
                              void* d_out, int out_size, void* d_ws, size_t ws_size,
                              hipStream_t stream)
{
    static const int exp_sizes[23] = {
        16384, 8192, 192, 64, 4096, 64,
        256, 64, 4096, 64,
        16384, 128, 8192, 128,
        8192, 128, 8192, 128,
        4096, 64, 128, 2, 1
    };
    // ws layout
    float* hv0 = (float*)d_ws;                  // 524288 f
    float* hv1 = hv0 + 524288;
    float* p0  = hv1 + 524288;
    float* p1  = p0  + 524288;
    float* dx  = p1  + 524288;                  // 16384 f
    float* u2_0T = dx + 16384;                  // 4096 f
    float* u2_1T = u2_0T + 4096;
    float* w1nT  = u2_1T + 4096;
    float* hw1T  = w1nT + 4096;
    float* biasB = hw1T + 4096;                 // 3 x 64 f
    float* biasC = biasB + 64;
    float* biasD = biasC + 64;
    _Float16* WF = (_Float16*)(biasD + 64);     // 16384 f16 (4 stages)
    u16* he0g  = (u16*)(WF + 16384);            // 8192*4608 u16 (75.5 MB)
    const size_t need = (size_t)((char*)(he0g + (size_t)8192 * HBLK) - (char*)d_ws);

    int bad = -1;
    if (n_in != 23 || out_size != 16384) bad = 98;
    else if (ws_size < need) bad = 97;
    else for (int i = 0; i < 23; ++i)
        if (in_sizes[i] != exp_sizes[i]) { bad = i; break; }
    if (bad >= 0) {
        k_beacon<<<1, 1, 0, stream>>>((float*)d_out, 2e6f + bad * 1e4f);
        return;
    }

    const float* x      = (const float*)d_in[0];
    const float* spin   = (const float*)d_in[1];
    const float* nw1    = (const float*)d_in[2];
    const float* nb1    = (const float*)d_in[3];
    const float* nw2    = (const float*)d_in[4];
    const float* nb2    = (const float*)d_in[5];
    const float* ew1    = (const float*)d_in[6];
    const float* eb1    = (const float*)d_in[7];
    const float* ew2    = (const float*)d_in[8];
    const float* eb2    = (const float*)d_in[9];
    const float* v2e_w1 = (const float*)d_in[10];
    const float* v2e_b1 = (const float*)d_in[11];
    const float* v2e_w2 = (const float*)d_in[12];
    const float* v2e_b2 = (const float*)d_in[13];
    const float* e2v_w1 = (const float*)d_in[14];
    const float* e2v_b1 = (const float*)d_in[15];
    const float* e2v_w2 = (const float*)d_in[16];
    const float* e2v_b2 = (const float*)d_in[17];
    const float* hw1    = (const float*)d_in[18];
    const float* hb1    = (const float*)d_in[19];
    const float* hw2    = (const float*)d_in[20];
    const float* hb2    = (const float*)d_in[21];
    const float* scale  = (const float*)d_in[22];

    // layer slices: w1he_l = v2e_w1 + l*8192 + 4096 (edge part); w1n_l = v2e_w1 + l*8192
    k_pre<<<2177, 256, 0, stream>>>(
        ew2, v2e_w1 + 4096, v2e_w2, e2v_w1,
        v2e_w1 + 12288, v2e_w2 + 4096, e2v_w1 + 4096,
        eb2, v2e_b2, e2v_b1, v2e_b2 + 64, e2v_b1 + 64,
        v2e_b1, v2e_b1 + 64,
        e2v_w2, e2v_w2 + 4096, v2e_w1 + 8192, hw1,
        WF, biasB, biasC, biasD,
        u2_0T, u2_1T, w1nT, hw1T,
        x, spin, nw1, nb1, nw2, nb2, v2e_w1, hv0, p0);
    k_L0<<<4096, 256, 0, stream>>>(x, ew1, eb1,
        p0, biasB, u2_0T, e2v_b2,
        WF, hv0, hv1,
        w1nT, biasC, p1,
        he0g);
    k_L1<<<4096, 256, 0, stream>>>(he0g,
        p1, biasD, u2_1T, e2v_b2 + 64,
        WF, hv1, hw1T, hb1, hw2, hb2, scale, dx);
    k_mean<<<128, 64, 0, stream>>>(dx, (float*)d_out);
}

// Round 8
// 205.596 us; speedup vs baseline: 1.2791x; 1.0318x over previous
//
#include <hip/hip_runtime.h>
#include <math.h>

// B=128, N=64, D=2, H=64, M=64, L=2. f32 in / f32 out.
// R25 = R24 (WIN: 212.1us, k_L0 70.4->61.1, prediction matched) scaled to
// FOUR j's per block (grid 2048). Confirmed mechanism: per-block time pinned
// by serial phase chain; amortizing it across j's pays ~proportionally.
// Enablers bundled (both de-risked by prior rounds):
//  - LDS aliasing: sred(4KB)->tA0, shv(1KB)->tA1 (reads of tA complete before
//    barrier 4; writes after it). 37.9KB total -> 4 blk/CU (vs 43KB -> 3).
//  - he0g store = linear b128 copy of tiles incl. pad cols (R19: safe, WRITE
//    +14MB benign, pads never read by MFMA addressing); replaces 64 scalar
//    u16 stores/thread at 4-j in an 84%-VALU-busy kernel.
// Prediction: k_L0 61->53-57, k_L1 -6-8, total ~196-205; VGPR ~70-100,
// LDS ~38KB, WRITE 77.8->~92MB. Falsify: k_L0 >= 60 -> revert to R24.
// DEAD BRANCHES (counter-verified): cross-block coherence tails (R15/16/R22
// he0g FETCH-poison); VGPR-cap theory (R23); launch-count fusion via atomics.
// Launch slots ~14us; container noise +-7%/kernel.
// Merged weights: SA=ew2@w1he0, SB=w2_0@u1_0(+biasB), SC=w2_0@w1he1, SD=w2_1@u1_1(+biasD);
// p0' carries b1_0+eb2@w1he0; p1' carries b1n+b2_0@w1he1 (biasC).
// MFMA fragment addressing identical to R9-R14 (verified).

typedef unsigned short u16;
typedef unsigned int u32;
typedef _Float16 half8 __attribute__((ext_vector_type(8)));   // 4 VGPR frag
typedef __attribute__((ext_vector_type(4))) float floatx4;

#define TS 72            // LDS tile row stride (f16): 144 B
#define HROW 72          // he0g row stride (u16) — mirrors LDS tile
#define HBLK (64 * HROW) // 4608 u16 per (b,j) tile
#define TILEB (64 * TS * 2)  // 9216 B per LDS tile

// gelu via A&S 7.1.27 rational erf (|eps|<=5e-4), no exp (R14-verified)
__device__ __forceinline__ float gelu_f(float x) {
    float s = fabsf(x) * 0.70710678118654752f;
    float q = fmaf(fmaf(fmaf(fmaf(0.078108f, s, 0.000972f), s, 0.230389f), s, 0.278393f), s, 1.0f);
    float q2 = q * q;
    float r = __builtin_amdgcn_rcpf(q2 * q2);
    float t = 0.5f * x * r;
    return x > 0.f ? x - t : t;
}

// k_pre: unchanged from R21 (verified).
__global__ __launch_bounds__(256) void k_pre(
    const float* __restrict__ ew2, const float* __restrict__ w1he0,
    const float* __restrict__ w2_0, const float* __restrict__ u1_0,
    const float* __restrict__ w1he1, const float* __restrict__ w2_1,
    const float* __restrict__ u1_1,
    const float* __restrict__ eb2, const float* __restrict__ b2_0,
    const float* __restrict__ c1_0, const float* __restrict__ b2_1,
    const float* __restrict__ c1_1,
    const float* __restrict__ b1_0v, const float* __restrict__ b1nv,
    const float* __restrict__ u2_0, const float* __restrict__ u2_1,
    const float* __restrict__ w1n, const float* __restrict__ hw1,
    _Float16* __restrict__ WF,
    float* __restrict__ biasB, float* __restrict__ biasC, float* __restrict__ biasD,
    float* __restrict__ u2_0T, float* __restrict__ u2_1T,
    float* __restrict__ w1nT, float* __restrict__ hw1T,
    const float* __restrict__ x, const float* __restrict__ spin,
    const float* __restrict__ nw1, const float* __restrict__ nb1,
    const float* __restrict__ nw2, const float* __restrict__ nb2,
    const float* __restrict__ w1_0,
    float* __restrict__ hv, float* __restrict__ p0)
{
    int blk = blockIdx.x;
    if (blk < 64) {
        int s = blk >> 4;                               // product id
        int idx = (blk & 15) * 256 + threadIdx.x;       // 0..4095
        int k = idx >> 6, n = idx & 63;
        const float *A, *Bm;
        if (s == 0)      { A = ew2;  Bm = w1he0; }
        else if (s == 1) { A = w2_0; Bm = u1_0;  }
        else if (s == 2) { A = w2_0; Bm = w1he1; }
        else             { A = w2_1; Bm = u1_1;  }
        float acc = 0.f;
        for (int q = 0; q < 64; ++q) acc = fmaf(A[k * 64 + q], Bm[q * 64 + n], acc);
        int kc = k >> 5, qd = (k >> 3) & 3, jj = k & 7;
        WF[(((s * 2 + kc) * 64 + n) * 4 + qd) * 8 + jj] = (_Float16)acc;
    } else if (blk == 64) {
        int s = threadIdx.x >> 6, cc = threadIdx.x & 63;
        if (s > 0) {
            const float *bv, *Bm, *add; float* dst;
            if (s == 1)      { bv = b2_0; Bm = u1_0;  add = c1_0; dst = biasB; }
            else if (s == 2) { bv = b2_0; Bm = w1he1; add = b1nv; dst = biasC; }
            else             { bv = b2_1; Bm = u1_1;  add = c1_1; dst = biasD; }
            float acc = add[cc];
            for (int q = 0; q < 64; ++q) acc = fmaf(bv[q], Bm[q * 64 + cc], acc);
            dst[cc] = acc;
        }
    } else if (blk < 129) {
        int idx = (blk - 65) * 256 + threadIdx.x;       // 0..16383
        int s = idx >> 12, r = idx & 4095, m = r >> 6, tc = r & 63;
        const float* W = s == 0 ? u2_0 : s == 1 ? u2_1 : s == 2 ? w1n : hw1;
        float* WT      = s == 0 ? u2_0T : s == 1 ? u2_1T : s == 2 ? w1nT : hw1T;
        WT[tc * 64 + m] = W[m * 64 + tc];
    } else {
        __shared__ float a[4][64];
        __shared__ float shv[4][64];
        int w = threadIdx.x >> 6, h = threadIdx.x & 63;
        int node = (blk - 129) * 4 + w;
        float2 xv = ((const float2*)x)[node];
        float sp = spin[node];
        float z = fmaf(xv.x, nw1[h], fmaf(xv.y, nw1[64 + h], fmaf(sp, nw1[128 + h], nb1[h])));
        a[w][h] = gelu_f(z);                         // wave-synchronous slice
        float acc = nb2[h];
        for (int k = 0; k < 64; ++k) acc = fmaf(a[w][k], nw2[k * 64 + h], acc);
        hv[node * 64 + h] = acc;
        shv[w][h] = acc;
        // p0' = b1_0 + eb2@w1he0 (biasA fold, inline) + hv@w1_0
        float pa = b1_0v[h];
        for (int q = 0; q < 64; ++q) pa = fmaf(eb2[q], w1he0[q * 64 + h], pa);
        for (int k = 0; k < 64; ++k) pa = fmaf(shv[w][k], w1_0[k * 64 + h], pa);
        p0[node * 64 + h] = pa;
    }
}

// quad-tile MFMA: shared B-fragment, four A-tiles (R9-verified addressing)
__device__ __forceinline__ void mfma_acc4(
    const _Float16* __restrict__ t0, const _Float16* __restrict__ t1,
    const _Float16* __restrict__ t2, const _Float16* __restrict__ t3,
    const _Float16* __restrict__ WF,
    int stage, int c, int quad, int nn,
    floatx4 a0[4], floatx4 a1[4], floatx4 a2[4], floatx4 a3[4])
{
    int sA = ((nn >> 2) & 3) << 3;
    #pragma unroll
    for (int kc = 0; kc < 2; ++kc) {
        half8 bf = *(const half8*)(WF + (((stage * 2 + kc) * 64 + c) * 4 + quad) * 8);
        int k0 = (kc * 32 + quad * 8) ^ sA;
        #pragma unroll
        for (int mt = 0; mt < 4; ++mt) {
            int off = (mt * 16 + nn) * TS + k0;
            a0[mt] = __builtin_amdgcn_mfma_f32_16x16x32_f16(*(const half8*)(t0 + off), bf, a0[mt], 0, 0, 0);
            a1[mt] = __builtin_amdgcn_mfma_f32_16x16x32_f16(*(const half8*)(t1 + off), bf, a1[mt], 0, 0, 0);
            a2[mt] = __builtin_amdgcn_mfma_f32_16x16x32_f16(*(const half8*)(t2 + off), bf, a2[mt], 0, 0, 0);
            a3[mt] = __builtin_amdgcn_mfma_f32_16x16x32_f16(*(const half8*)(t3 + off), bf, a3[mt], 0, 0, 0);
        }
    }
}

__device__ __forceinline__ void init_bias(floatx4 acc[4], float bc) {
    #pragma unroll
    for (int mt = 0; mt < 4; ++mt) acc[mt] = (floatx4){bc, bc, bc, bc};
}
__device__ __forceinline__ void init_p(floatx4 acc[4], const float* __restrict__ p,
                                       int rowbase, int c, int quad) {
    #pragma unroll
    for (int mt = 0; mt < 4; ++mt)
        #pragma unroll
        for (int r = 0; r < 4; ++r)
            acc[mt][r] = p[(rowbase + mt * 16 + quad * 4 + r) * 64 + c];
}

__global__ __launch_bounds__(256, 4) void k_L0(
    const float* __restrict__ x,
    const float* __restrict__ ew1, const float* __restrict__ eb1,
    const float* __restrict__ p0,        // p0' (biasA folded), per (b,i)
    const float* __restrict__ biasB,
    const float* __restrict__ u2_0T, const float* __restrict__ c2_0,
    const _Float16* __restrict__ WF,
    const float* __restrict__ hv0, float* __restrict__ hv1,
    const float* __restrict__ w1nT, const float* __restrict__ biasC,
    float* __restrict__ p1,
    u16* __restrict__ he0g)
{
    __shared__ __align__(16) char smem[4 * TILEB + 1024];   // 37.9 KB
    _Float16* tA0 = (_Float16*)smem;
    _Float16* tA1 = (_Float16*)(smem + TILEB);
    _Float16* tA2 = (_Float16*)(smem + 2 * TILEB);
    _Float16* tA3 = (_Float16*)(smem + 3 * TILEB);
    float* sS   = (float*)(smem + 4 * TILEB);   // [4][64], dedicated
    float* sred = (float*)smem;                  // [4][256] aliases tA0 (barrier-protected)
    float* shv  = (float*)(smem + TILEB);        // [4][64]  aliases tA1 (barrier-protected)

    int t = threadIdx.x, L = t & 63;
    int w = __builtin_amdgcn_readfirstlane(t >> 6);
    int nn = L & 15, quad = L >> 4;
    int c = w * 16 + nn;
    int cw = c ^ (quad << 3);
    int b = blockIdx.x >> 4, jp = blockIdx.x & 15;
    int j0 = jp * 4, j1 = j0 + 1, j2 = j0 + 2, j3 = j0 + 3;

    // geometry: lane = i = L; four destinations
    float2 xi = ((const float2*)x)[b * 64 + L];
    float2 xja = ((const float2*)x)[b * 64 + j0];
    float2 xjb = ((const float2*)x)[b * 64 + j1];
    float2 xjc = ((const float2*)x)[b * 64 + j2];
    float2 xjd = ((const float2*)x)[b * 64 + j3];
    float da0 = xja.x - xi.x, da1 = xja.y - xi.y;
    float db0 = xjb.x - xi.x, db1 = xjb.y - xi.y;
    float dc0 = xjc.x - xi.x, dc1 = xjc.y - xi.y;
    float dd0_ = xjd.x - xi.x, dd1_ = xjd.y - xi.y;
    float r2a = fmaf(da0, da0, da1 * da1), rra = sqrtf(r2a + 1e-12f);
    float r2b = fmaf(db0, db0, db1 * db1), rrb = sqrtf(r2b + 1e-12f);
    float r2c = fmaf(dc0, dc0, dc1 * dc1), rrc = sqrtf(r2c + 1e-12f);
    float r2d = fmaf(dd0_, dd0_, dd1_ * dd1_), rrd = sqrtf(r2d + 1e-12f);
    int swL = ((L >> 2) & 3) << 3;

    // g1 rows for all four j (ew1/eb1 SGPR loads shared)
    #pragma unroll
    for (int mb = 0; mb < 2; ++mb) {
        int m0 = w * 16 + mb * 8;
        half8 ha, hb, hc, hd;
        #pragma unroll
        for (int kk = 0; kk < 8; ++kk) {
            int m = m0 + kk;
            float e0 = ew1[m], e1 = ew1[64 + m], e2 = ew1[128 + m], e3 = ew1[192 + m], e4 = eb1[m];
            ha[kk] = (_Float16)gelu_f(fmaf(da0, e0, fmaf(da1, e1, fmaf(rra, e2, fmaf(r2a, e3, e4)))));
            hb[kk] = (_Float16)gelu_f(fmaf(db0, e0, fmaf(db1, e1, fmaf(rrb, e2, fmaf(r2b, e3, e4)))));
            hc[kk] = (_Float16)gelu_f(fmaf(dc0, e0, fmaf(dc1, e1, fmaf(rrc, e2, fmaf(r2c, e3, e4)))));
            hd[kk] = (_Float16)gelu_f(fmaf(dd0_, e0, fmaf(dd1_, e1, fmaf(rrd, e2, fmaf(r2d, e3, e4)))));
        }
        int o = L * TS + (m0 ^ swL);
        *(half8*)(tA0 + o) = ha;
        *(half8*)(tA1 + o) = hb;
        *(half8*)(tA2 + o) = hc;
        *(half8*)(tA3 + o) = hd;
    }
    __syncthreads();                                  // (1) g1 ready

    floatx4 acc0[4], acc1[4], acc2[4], acc3[4];
    // M1: z0 = p0' + g1 @ SA (p0 rows shared across j)
    init_p(acc0, p0, b * 64, c, quad);
    #pragma unroll
    for (int mt = 0; mt < 4; ++mt) { acc1[mt] = acc0[mt]; acc2[mt] = acc0[mt]; acc3[mt] = acc0[mt]; }
    mfma_acc4(tA0, tA1, tA2, tA3, WF, 0, c, quad, nn, acc0, acc1, acc2, acc3);
    __syncthreads();                                  // (2) tA reads done
    #pragma unroll
    for (int mt = 0; mt < 4; ++mt)
        #pragma unroll
        for (int r = 0; r < 4; ++r) {
            int i = mt * 16 + quad * 4 + r;
            tA0[i * TS + cw] = (_Float16)gelu_f(acc0[mt][r]);
            tA1[i * TS + cw] = (_Float16)gelu_f(acc1[mt][r]);
            tA2[i * TS + cw] = (_Float16)gelu_f(acc2[mt][r]);
            tA3[i * TS + cw] = (_Float16)gelu_f(acc3[mt][r]);
        }
    __syncthreads();                                  // (3) Y visible
    // he0g: linear b128 copy of tiles (incl. pads — never read; R19-safe)
    {
        float4* dst = (float4*)(he0g + (size_t)(b * 64 + j0) * HBLK);
        const float4* src = (const float4*)smem;
        #pragma unroll
        for (int q = 0; q < 9; ++q)
            dst[t + q * 256] = src[t + q * 256];      // 2304 float4 = 4 tiles
    }
    // M2: a = gelu(Y @ SB + biasB); masked i-sums
    {
        float bb = biasB[c];
        init_bias(acc0, bb); init_bias(acc1, bb); init_bias(acc2, bb); init_bias(acc3, bb);
    }
    mfma_acc4(tA0, tA1, tA2, tA3, WF, 1, c, quad, nn, acc0, acc1, acc2, acc3);
    {
        float s0 = 0.f, s1 = 0.f, s2 = 0.f, s3 = 0.f;
        #pragma unroll
        for (int mt = 0; mt < 4; ++mt)
            #pragma unroll
            for (int r = 0; r < 4; ++r) {
                int i = mt * 16 + quad * 4 + r;
                s0 += (i == j0) ? 0.f : gelu_f(acc0[mt][r]);
                s1 += (i == j1) ? 0.f : gelu_f(acc1[mt][r]);
                s2 += (i == j2) ? 0.f : gelu_f(acc2[mt][r]);
                s3 += (i == j3) ? 0.f : gelu_f(acc3[mt][r]);
            }
        s0 += __shfl_xor(s0, 16); s0 += __shfl_xor(s0, 32);
        s1 += __shfl_xor(s1, 16); s1 += __shfl_xor(s1, 32);
        s2 += __shfl_xor(s2, 16); s2 += __shfl_xor(s2, 32);
        s3 += __shfl_xor(s3, 16); s3 += __shfl_xor(s3, 32);
        if (quad == 0) { sS[c] = s0; sS[64 + c] = s1; sS[128 + c] = s2; sS[192 + c] = s3; }
    }
    __syncthreads();                                  // (4) sS ready; tA reads done -> aliases live
    // tail A: hv1 dots, u2_0T columns shared across 4 j
    {
        const float4* uv4 = (const float4*)(u2_0T + L * 64 + w * 16);
        float g0 = 0.f, g1 = 0.f, g2 = 0.f, g3 = 0.f;
        #pragma unroll
        for (int m4 = 0; m4 < 4; ++m4) {
            float4 uv = uv4[m4];
            float4 v0 = ((const float4*)(sS + w * 16))[m4];
            float4 v1 = ((const float4*)(sS + 64 + w * 16))[m4];
            float4 v2 = ((const float4*)(sS + 128 + w * 16))[m4];
            float4 v3 = ((const float4*)(sS + 192 + w * 16))[m4];
            g0 = fmaf(v0.x, uv.x, fmaf(v0.y, uv.y, fmaf(v0.z, uv.z, fmaf(v0.w, uv.w, g0))));
            g1 = fmaf(v1.x, uv.x, fmaf(v1.y, uv.y, fmaf(v1.z, uv.z, fmaf(v1.w, uv.w, g1))));
            g2 = fmaf(v2.x, uv.x, fmaf(v2.y, uv.y, fmaf(v2.z, uv.z, fmaf(v2.w, uv.w, g2))));
            g3 = fmaf(v3.x, uv.x, fmaf(v3.y, uv.y, fmaf(v3.z, uv.z, fmaf(v3.w, uv.w, g3))));
        }
        sred[0 * 256 + w * 64 + L] = g0;
        sred[1 * 256 + w * 64 + L] = g1;
        sred[2 * 256 + w * 64 + L] = g2;
        sred[3 * 256 + w * 64 + L] = g3;
    }
    __syncthreads();                                  // (5) sred ready
    {
        int h = t & 63, sj = t >> 6;
        const float* sr = sred + sj * 256;
        float g = sr[h] + sr[64 + h] + sr[128 + h] + sr[192 + h];
        int o = (b * 64 + j0 + sj) * 64 + h;
        float hvv = hv0[o] + g * (1.0f / 63.0f) + c2_0[h];
        hv1[o] = hvv;
        shv[sj * 64 + h] = hvv;
    }
    __syncthreads();                                  // (6) shv ready
    // tail B: p1' dots, w1nT columns shared
    {
        const float4* wv4 = (const float4*)(w1nT + L * 64 + w * 16);
        float p0_ = 0.f, p1_ = 0.f, p2_ = 0.f, p3_ = 0.f;
        #pragma unroll
        for (int m4 = 0; m4 < 4; ++m4) {
            float4 wv = wv4[m4];
            float4 v0 = ((const float4*)(shv + w * 16))[m4];
            float4 v1 = ((const float4*)(shv + 64 + w * 16))[m4];
            float4 v2 = ((const float4*)(shv + 128 + w * 16))[m4];
            float4 v3 = ((const float4*)(shv + 192 + w * 16))[m4];
            p0_ = fmaf(v0.x, wv.x, fmaf(v0.y, wv.y, fmaf(v0.z, wv.z, fmaf(v0.w, wv.w, p0_))));
            p1_ = fmaf(v1.x, wv.x, fmaf(v1.y, wv.y, fmaf(v1.z, wv.z, fmaf(v1.w, wv.w, p1_))));
            p2_ = fmaf(v2.x, wv.x, fmaf(v2.y, wv.y, fmaf(v2.z, wv.z, fmaf(v2.w, wv.w, p2_))));
            p3_ = fmaf(v3.x, wv.x, fmaf(v3.y, wv.y, fmaf(v3.z, wv.z, fmaf(v3.w, wv.w, p3_))));
        }
        __syncthreads();                              // (7) shv reads done -> sred reusable
        sred[0 * 256 + w * 64 + L] = p0_;
        sred[1 * 256 + w * 64 + L] = p1_;
        sred[2 * 256 + w * 64 + L] = p2_;
        sred[3 * 256 + w * 64 + L] = p3_;
    }
    __syncthreads();                                  // (8) sred ready
    {
        int h = t & 63, sj = t >> 6;
        const float* sr = sred + sj * 256;
        p1[(b * 64 + j0 + sj) * 64 + h] = biasC[h] + sr[h] + sr[64 + h] + sr[128 + h] + sr[192 + h];
    }
}

__global__ __launch_bounds__(256, 4) void k_L1(
    const u16* __restrict__ he0g,
    const float* __restrict__ p1,        // p1' (biasC folded), per (b,i)
    const float* __restrict__ biasD,
    const float* __restrict__ u2_1T, const float* __restrict__ c2_1,
    const _Float16* __restrict__ WF,
    const float* __restrict__ hv1,
    const float* __restrict__ hw1T, const float* __restrict__ hb1,
    const float* __restrict__ hw2, const float* __restrict__ hb2,
    const float* __restrict__ scale, float* __restrict__ dx)
{
    __shared__ __align__(16) char smem[4 * TILEB + 1024];
    _Float16* tA0 = (_Float16*)smem;
    _Float16* tA1 = (_Float16*)(smem + TILEB);
    _Float16* tA2 = (_Float16*)(smem + 2 * TILEB);
    _Float16* tA3 = (_Float16*)(smem + 3 * TILEB);
    float* sS   = (float*)(smem + 4 * TILEB);
    float* sred = (float*)smem;                  // aliases tA0
    float* shv  = (float*)(smem + TILEB);        // aliases tA1

    int t = threadIdx.x, L = t & 63;
    int w = __builtin_amdgcn_readfirstlane(t >> 6);
    int nn = L & 15, quad = L >> 4;
    int c = w * 16 + nn;
    int cw = c ^ (quad << 3);
    int b = blockIdx.x >> 4, jp = blockIdx.x & 15;
    int j0 = jp * 4, j1 = j0 + 1, j2 = j0 + 2, j3 = j0 + 3;

    {   // Y load: 4 tiles, linear float4 copy (pads included, never read)
        const float4* src = (const float4*)(he0g + (size_t)(b * 64 + j0) * HBLK);
        float4* dst = (float4*)smem;
        #pragma unroll
        for (int q = 0; q < 9; ++q)
            dst[t + q * 256] = src[t + q * 256];
    }
    __syncthreads();                                  // (1) Y ready

    floatx4 acc0[4], acc1[4], acc2[4], acc3[4];
    // M3: z1 = p1' + Y @ SC (p1 rows shared across j)
    init_p(acc0, p1, b * 64, c, quad);
    #pragma unroll
    for (int mt = 0; mt < 4; ++mt) { acc1[mt] = acc0[mt]; acc2[mt] = acc0[mt]; acc3[mt] = acc0[mt]; }
    mfma_acc4(tA0, tA1, tA2, tA3, WF, 2, c, quad, nn, acc0, acc1, acc2, acc3);
    __syncthreads();                                  // (2) tA reads done
    #pragma unroll
    for (int mt = 0; mt < 4; ++mt)
        #pragma unroll
        for (int r = 0; r < 4; ++r) {
            int i = mt * 16 + quad * 4 + r;
            tA0[i * TS + cw] = (_Float16)gelu_f(acc0[mt][r]);
            tA1[i * TS + cw] = (_Float16)gelu_f(acc1[mt][r]);
            tA2[i * TS + cw] = (_Float16)gelu_f(acc2[mt][r]);
            tA3[i * TS + cw] = (_Float16)gelu_f(acc3[mt][r]);
        }
    __syncthreads();                                  // (3) Y2 visible
    // M4: a = gelu(Y2 @ SD + biasD); masked i-sums
    {
        float bd = biasD[c];
        init_bias(acc0, bd); init_bias(acc1, bd); init_bias(acc2, bd); init_bias(acc3, bd);
    }
    mfma_acc4(tA0, tA1, tA2, tA3, WF, 3, c, quad, nn, acc0, acc1, acc2, acc3);
    {
        float s0 = 0.f, s1 = 0.f, s2 = 0.f, s3 = 0.f;
        #pragma unroll
        for (int mt = 0; mt < 4; ++mt)
            #pragma unroll
            for (int r = 0; r < 4; ++r) {
                int i = mt * 16 + quad * 4 + r;
                s0 += (i == j0) ? 0.f : gelu_f(acc0[mt][r]);
                s1 += (i == j1) ? 0.f : gelu_f(acc1[mt][r]);
                s2 += (i == j2) ? 0.f : gelu_f(acc2[mt][r]);
                s3 += (i == j3) ? 0.f : gelu_f(acc3[mt][r]);
            }
        s0 += __shfl_xor(s0, 16); s0 += __shfl_xor(s0, 32);
        s1 += __shfl_xor(s1, 16); s1 += __shfl_xor(s1, 32);
        s2 += __shfl_xor(s2, 16); s2 += __shfl_xor(s2, 32);
        s3 += __shfl_xor(s3, 16); s3 += __shfl_xor(s3, 32);
        if (quad == 0) { sS[c] = s0; sS[64 + c] = s1; sS[128 + c] = s2; sS[192 + c] = s3; }
    }
    __syncthreads();                                  // (4) sS ready; aliases live
    // tail A: hv2 dots
    {
        const float4* uv4 = (const float4*)(u2_1T + L * 64 + w * 16);
        float g0 = 0.f, g1 = 0.f, g2 = 0.f, g3 = 0.f;
        #pragma unroll
        for (int m4 = 0; m4 < 4; ++m4) {
            float4 uv = uv4[m4];
            float4 v0 = ((const float4*)(sS + w * 16))[m4];
            float4 v1 = ((const float4*)(sS + 64 + w * 16))[m4];
            float4 v2 = ((const float4*)(sS + 128 + w * 16))[m4];
            float4 v3 = ((const float4*)(sS + 192 + w * 16))[m4];
            g0 = fmaf(v0.x, uv.x, fmaf(v0.y, uv.y, fmaf(v0.z, uv.z, fmaf(v0.w, uv.w, g0))));
            g1 = fmaf(v1.x, uv.x, fmaf(v1.y, uv.y, fmaf(v1.z, uv.z, fmaf(v1.w, uv.w, g1))));
            g2 = fmaf(v2.x, uv.x, fmaf(v2.y, uv.y, fmaf(v2.z, uv.z, fmaf(v2.w, uv.w, g2))));
            g3 = fmaf(v3.x, uv.x, fmaf(v3.y, uv.y, fmaf(v3.z, uv.z, fmaf(v3.w, uv.w, g3))));
        }
        sred[0 * 256 + w * 64 + L] = g0;
        sred[1 * 256 + w * 64 + L] = g1;
        sred[2 * 256 + w * 64 + L] = g2;
        sred[3 * 256 + w * 64 + L] = g3;
    }
    __syncthreads();                                  // (5) sred ready
    {
        int h = t & 63, sj = t >> 6;
        const float* sr = sred + sj * 256;
        float g = sr[h] + sr[64 + h] + sr[128 + h] + sr[192 + h];
        float hv2 = hv1[(b * 64 + j0 + sj) * 64 + h] + g * (1.0f / 63.0f) + c2_1[h];
        shv[sj * 64 + h] = hv2;
    }
    __syncthreads();                                  // (6) shv ready
    // tail B: head layer-1 dots
    {
        const float4* wv4 = (const float4*)(hw1T + L * 64 + w * 16);
        float a0 = 0.f, a1 = 0.f, a2 = 0.f, a3 = 0.f;
        #pragma unroll
        for (int m4 = 0; m4 < 4; ++m4) {
            float4 wv = wv4[m4];
            float4 v0 = ((const float4*)(shv + w * 16))[m4];
            float4 v1 = ((const float4*)(shv + 64 + w * 16))[m4];
            float4 v2 = ((const float4*)(shv + 128 + w * 16))[m4];
            float4 v3 = ((const float4*)(shv + 192 + w * 16))[m4];
            a0 = fmaf(v0.x, wv.x, fmaf(v0.y, wv.y, fmaf(v0.z, wv.z, fmaf(v0.w, wv.w, a0))));
            a1 = fmaf(v1.x, wv.x, fmaf(v1.y, wv.y, fmaf(v1.z, wv.z, fmaf(v1.w, wv.w, a1))));
            a2 = fmaf(v2.x, wv.x, fmaf(v2.y, wv.y, fmaf(v2.z, wv.z, fmaf(v2.w, wv.w, a2))));
            a3 = fmaf(v3.x, wv.x, fmaf(v3.y, wv.y, fmaf(v3.z, wv.z, fmaf(v3.w, wv.w, a3))));
        }
        __syncthreads();                              // (7) shv reads done
        sred[0 * 256 + w * 64 + L] = a0;
        sred[1 * 256 + w * 64 + L] = a1;
        sred[2 * 256 + w * 64 + L] = a2;
        sred[3 * 256 + w * 64 + L] = a3;
    }
    __syncthreads();                                  // (8) sred ready
    {
        int h = t & 63, sj = t >> 6;   // wave sj -> j0+sj
        const float* sr = sred + sj * 256;
        float a = hb1[h] + sr[h] + sr[64 + h] + sr[128 + h] + sr[192 + h];
        float t1 = tanhf(a);
        float dd0 = t1 * hw2[h * 2], dd1 = t1 * hw2[h * 2 + 1];
        #pragma unroll
        for (int off = 1; off <= 32; off <<= 1) { dd0 += __shfl_xor(dd0, off); dd1 += __shfl_xor(dd1, off); }
        if (h == 0) {
            float sp = log1pf(__expf(scale[0]));
            dx[(b * 64 + j0 + sj) * 2 + 0] = (dd0 + hb2[0]) * sp;
            dx[(b * 64 + j0 + sj) * 2 + 1] = (dd1 + hb2[1]) * sp;
        }
    }
}

__global__ __launch_bounds__(64) void k_mean(
    const float* __restrict__ dx, float* __restrict__ out)
{
    __shared__ float s0[64], s1[64];
    int b = blockIdx.x, j = threadIdx.x;
    float2 d = ((const float2*)dx)[b * 64 + j];
    s0[j] = d.x; s1[j] = d.y;
    __syncthreads();
    float m0 = 0.f, m1 = 0.f;
    for (int q = 0; q < 64; ++q) { m0 += s0[q]; m1 += s1[q]; }
    ((float2*)out)[b * 64 + j] = make_float2(d.x - m0 * (1.0f / 64.0f), d.y - m1 * (1.0f / 64.0f));
}

__global__ void k_beacon(float* out, float code) { out[0] = code; }

extern "C" void kernel_launch(void* const* d_in, const int* in_sizes, int n_in,
                              void* d_out, int out_size, void* d_ws, size_t ws_size,
                              hipStream_t stream)
{
    static const int exp_sizes[23] = {
        16384, 8192, 192, 64, 4096, 64,
        256, 64, 4096, 64,
        16384, 128, 8192, 128,
        8192, 128, 8192, 128,
        4096, 64, 128, 2, 1
    };
    // ws layout
    float* hv0 = (float*)d_ws;                  // 524288 f
    float* hv1 = hv0 + 524288;
    float* p0  = hv1 + 524288;
    float* p1  = p0  + 524288;
    float* dx  = p1  + 524288;                  // 16384 f
    float* u2_0T = dx + 16384;                  // 4096 f
    float* u2_1T = u2_0T + 4096;
    float* w1nT  = u2_1T + 4096;
    float* hw1T  = w1nT + 4096;
    float* biasB = hw1T + 4096;                 // 3 x 64 f
    float* biasC = biasB + 64;
    float* biasD = biasC + 64;
    _Float16* WF = (_Float16*)(biasD + 64);     // 16384 f16 (4 stages)
    u16* he0g  = (u16*)(WF + 16384);            // 8192*4608 u16 (75.5 MB)
    const size_t need = (size_t)((char*)(he0g + (size_t)8192 * HBLK) - (char*)d_ws);

    int bad = -1;
    if (n_in != 23 || out_size != 16384) bad = 98;
    else if (ws_size < need) bad = 97;
    else for (int i = 0; i < 23; ++i)
        if (in_sizes[i] != exp_sizes[i]) { bad = i; break; }
    if (bad >= 0) {
        k_beacon<<<1, 1, 0, stream>>>((float*)d_out, 2e6f + bad * 1e4f);
        return;
    }

    const float* x      = (const float*)d_in[0];
    const float* spin   = (const float*)d_in[1];
    const float* nw1    = (const float*)d_in[2];
    const float* nb1    = (const float*)d_in[3];
    const float* nw2    = (const float*)d_in[4];
    const float* nb2    = (const float*)d_in[5];
    const float* ew1    = (const float*)d_in[6];
    const float* eb1    = (const float*)d_in[7];
    const float* ew2    = (const float*)d_in[8];
    const float* eb2    = (const float*)d_in[9];
    const float* v2e_w1 = (const float*)d_in[10];
    const float* v2e_b1 = (const float*)d_in[11];
    const float* v2e_w2 = (const float*)d_in[12];
    const float* v2e_b2 = (const float*)d_in[13];
    const float* e2v_w1 = (const float*)d_in[14];
    const float* e2v_b1 = (const float*)d_in[15];
    const float* e2v_w2 = (const float*)d_in[16];
    const float* e2v_b2 = (const float*)d_in[17];
    const float* hw1    = (const float*)d_in[18];
    const float* hb1    = (const float*)d_in[19];
    const float* hw2    = (const float*)d_in[20];
    const float* hb2    = (const float*)d_in[21];
    const float* scale  = (const float*)d_in[22];

    // layer slices: w1he_l = v2e_w1 + l*8192 + 4096 (edge part); w1n_l = v2e_w1 + l*8192
    k_pre<<<2177, 256, 0, stream>>>(
        ew2, v2e_w1 + 4096, v2e_w2, e2v_w1,
        v2e_w1 + 12288, v2e_w2 + 4096, e2v_w1 + 4096,
        eb2, v2e_b2, e2v_b1, v2e_b2 + 64, e2v_b1 + 64,
        v2e_b1, v2e_b1 + 64,
        e2v_w2, e2v_w2 + 4096, v2e_w1 + 8192, hw1,
        WF, biasB, biasC, biasD,
        u2_0T, u2_1T, w1nT, hw1T,
        x, spin, nw1, nb1, nw2, nb2, v2e_w1, hv0, p0);
    k_L0<<<2048, 256, 0, stream>>>(x, ew1, eb1,
        p0, biasB, u2_0T, e2v_b2,
        WF, hv0, hv1,
        w1nT, biasC, p1,
        he0g);
    k_L1<<<2048, 256, 0, stream>>>(he0g,
        p1, biasD, u2_1T, e2v_b2 + 64,
        WF, hv1, hw1T, hb1, hw2, hb2, scale, dx);
    k_mean<<<128, 64, 0, stream>>>(dx, (float*)d_out);
}